// Round 2
// baseline (509.596 us; speedup 1.0000x reference)
//
#include <hip/hip_runtime.h>
#include <hip/hip_bf16.h>

// RGCN basis-decomposition forward, hardened:
//  - no dynamic LDS, static LDS <= 32KB everywhere
//  - workspace usage branches on ws_size (host-side, constant per session)
//
// Path A (ws >= 102.4MB): Wfeat[n][r][:] = feat[n] @ W_r   (bf16 table)
//                         edge: out[dst] += norm * Wfeat[src][et]      (128B/edge)
// Path B (ws >= 51.2MB):  proj[n][b][:] = feat[n] @ V_b    (bf16 table)
//                         edge: out[dst] += norm * sum_b wc[et][b]*proj[src][b]
// Path C (no ws):         edge recomputes matvec from feat with V in LDS.
// All paths: out[n] = h_bias + feat[n] @ loop_weight, then edge-atomics on top.

constexpr int NNODES = 100000;
constexpr int NEDGES = 1600000;

// ---------------------------------------------------------------------------
// K1: 32 nodes / block (4 waves x 8 nodes), lane = output column.
// feat tile in 8KB static LDS; V + loop_w read from global (L1/L2 broadcast).
// PATH: 0 -> write Wfeat[N][8][64], 1 -> write proj[N][4][64], 2 -> out only.
// ---------------------------------------------------------------------------
template <int PATH>
__global__ __launch_bounds__(256)
void rgcn_proj_kernel(const float* __restrict__ feat,
                      const float* __restrict__ weight,   // [4][64][64]
                      const float* __restrict__ w_comp,   // [8][4]
                      const float* __restrict__ h_bias,   // [64]
                      const float* __restrict__ loop_w,   // [64][64]
                      __hip_bfloat16* __restrict__ table,
                      float* __restrict__ out)            // [N][64]
{
    __shared__ float featl[32 * 64];  // 8 KB

    const int t = threadIdx.x;
    const int nbase = blockIdx.x * 32;

    {   // stage feat tile, coalesced float4
        const float4* fsrc = (const float4*)(feat + (size_t)nbase * 64);
        float4* fdst = (float4*)featl;
        fdst[t] = fsrc[t];
        fdst[t + 256] = fsrc[t + 256];
    }

    const int lane = t & 63;
    const int n0 = (t >> 6) * 8;    // first node of this wave within block
    const float bias = h_bias[lane];

    __syncthreads();

    constexpr int NM = (PATH == 2) ? 1 : 5;   // 4 bases + loop, or loop only
    float acc[8][NM];
    #pragma unroll
    for (int n = 0; n < 8; ++n)
        #pragma unroll
        for (int m = 0; m < NM; ++m)
            acc[n][m] = 0.0f;

    #pragma unroll 4
    for (int i0 = 0; i0 < 64; i0 += 4) {
        float4 f4[8];
        #pragma unroll
        for (int n = 0; n < 8; ++n)   // LDS broadcast reads (uniform addr/wave)
            f4[n] = *(const float4*)&featl[(n0 + n) * 64 + i0];
        #pragma unroll
        for (int q = 0; q < 4; ++q) {
            const int i = i0 + q;
            float vv[NM];
            if (PATH < 2) {
                #pragma unroll
                for (int b = 0; b < 4; ++b)           // coalesced, L1/L2-hot
                    vv[b] = weight[b * 4096 + i * 64 + lane];
                vv[4] = loop_w[i * 64 + lane];
            } else {
                vv[0] = loop_w[i * 64 + lane];
            }
            #pragma unroll
            for (int n = 0; n < 8; ++n) {
                const float fv = (q == 0) ? f4[n].x : (q == 1) ? f4[n].y
                               : (q == 2) ? f4[n].z : f4[n].w;
                #pragma unroll
                for (int m = 0; m < NM; ++m)
                    acc[n][m] = fmaf(fv, vv[m], acc[n][m]);
            }
        }
    }

    // epilogue
    float wc[8][4];
    if (PATH == 0) {
        #pragma unroll
        for (int r = 0; r < 8; ++r)
            #pragma unroll
            for (int b = 0; b < 4; ++b)
                wc[r][b] = w_comp[r * 4 + b];
    }

    #pragma unroll
    for (int n = 0; n < 8; ++n) {
        const size_t gn = (size_t)(nbase + n0 + n);
        out[gn * 64 + lane] = bias + acc[n][NM - 1];   // bias + self-loop
        if (PATH == 0) {
            #pragma unroll
            for (int r = 0; r < 8; ++r) {
                const float w = fmaf(wc[r][0], acc[n][0],
                                fmaf(wc[r][1], acc[n][1],
                                fmaf(wc[r][2], acc[n][2],
                                     wc[r][3] * acc[n][3])));
                table[gn * 512 + (size_t)r * 64 + lane] = __float2bfloat16(w);
            }
        } else if (PATH == 1) {
            #pragma unroll
            for (int b = 0; b < 4; ++b)
                table[gn * 256 + (size_t)b * 64 + lane] = __float2bfloat16(acc[n][b]);
        }
    }
}

// ---------------------------------------------------------------------------
// K2-A: gather 128B/edge from Wfeat, 64 f32 atomics/edge.
// ---------------------------------------------------------------------------
__global__ __launch_bounds__(256)
void rgcn_edge_a(const int* __restrict__ src, const int* __restrict__ dst,
                 const int* __restrict__ et, const float* __restrict__ norm,
                 const __hip_bfloat16* __restrict__ wfeat,
                 float* __restrict__ out)
{
    const int lane = threadIdx.x & 63;
    const int wid  = (int)((blockIdx.x * blockDim.x + threadIdx.x) >> 6);
    const int nw   = (int)((gridDim.x * blockDim.x) >> 6);

    for (int e = wid; e < NEDGES; e += nw) {
        const int   s  = src[e];
        const int   d  = dst[e];
        const int   r  = et[e];
        const float nm = norm[e];
        const float w  = __bfloat162float(wfeat[(size_t)s * 512 + (size_t)r * 64 + lane]);
        atomicAdd(out + (size_t)d * 64 + lane, w * nm);
    }
}

// ---------------------------------------------------------------------------
// K2-B: gather 512B/edge from proj, combine with w_comp in-register.
// ---------------------------------------------------------------------------
__global__ __launch_bounds__(256)
void rgcn_edge_b(const int* __restrict__ src, const int* __restrict__ dst,
                 const int* __restrict__ et, const float* __restrict__ norm,
                 const __hip_bfloat16* __restrict__ proj,
                 const float* __restrict__ w_comp,
                 float* __restrict__ out)
{
    const int lane = threadIdx.x & 63;
    const int wid  = (int)((blockIdx.x * blockDim.x + threadIdx.x) >> 6);
    const int nw   = (int)((gridDim.x * blockDim.x) >> 6);

    for (int e = wid; e < NEDGES; e += nw) {
        const int   s  = src[e];
        const int   d  = dst[e];
        const int   r  = et[e];
        const float nm = norm[e];
        const __hip_bfloat16* p = proj + (size_t)s * 256;
        float m = w_comp[r * 4 + 0] * __bfloat162float(p[lane]);
        m = fmaf(w_comp[r * 4 + 1], __bfloat162float(p[ 64 + lane]), m);
        m = fmaf(w_comp[r * 4 + 2], __bfloat162float(p[128 + lane]), m);
        m = fmaf(w_comp[r * 4 + 3], __bfloat162float(p[192 + lane]), m);
        atomicAdd(out + (size_t)d * 64 + lane, m * nm);
    }
}

// ---------------------------------------------------------------------------
// K2-C: no workspace. Per-edge matvec; V staged bf16 in 32KB static LDS.
// ---------------------------------------------------------------------------
__global__ __launch_bounds__(256)
void rgcn_edge_c(const int* __restrict__ src, const int* __restrict__ dst,
                 const int* __restrict__ et, const float* __restrict__ norm,
                 const float* __restrict__ feat,
                 const float* __restrict__ weight,
                 const float* __restrict__ w_comp,
                 float* __restrict__ out)
{
    __shared__ __hip_bfloat16 Vl[4 * 64 * 64];  // 32 KB

    const int t = threadIdx.x;
    #pragma unroll
    for (int k = 0; k < 64; ++k)
        Vl[t + k * 256] = __float2bfloat16(weight[t + k * 256]);
    __syncthreads();

    const int lane = t & 63;
    const int wid  = (int)((blockIdx.x * blockDim.x + t) >> 6);
    const int nw   = (int)((gridDim.x * blockDim.x) >> 6);

    for (int e = wid; e < NEDGES; e += nw) {
        const int   s  = src[e];
        const int   d  = dst[e];
        const int   r  = et[e];
        const float nm = norm[e];
        const float wc0 = w_comp[r * 4 + 0], wc1 = w_comp[r * 4 + 1];
        const float wc2 = w_comp[r * 4 + 2], wc3 = w_comp[r * 4 + 3];
        const float f = feat[(size_t)s * 64 + lane];
        float acc = 0.0f;
        #pragma unroll 8
        for (int i = 0; i < 64; ++i) {
            const float fi = __shfl(f, i);
            float w =        wc0 * __bfloat162float(Vl[          i * 64 + lane]);
            w = fmaf(wc1, __bfloat162float(Vl[4096 + i * 64 + lane]), w);
            w = fmaf(wc2, __bfloat162float(Vl[8192 + i * 64 + lane]), w);
            w = fmaf(wc3, __bfloat162float(Vl[12288 + i * 64 + lane]), w);
            acc = fmaf(fi, w, acc);
        }
        atomicAdd(out + (size_t)d * 64 + lane, acc * nm);
    }
}

// ---------------------------------------------------------------------------
extern "C" void kernel_launch(void* const* d_in, const int* in_sizes, int n_in,
                              void* d_out, int out_size, void* d_ws, size_t ws_size,
                              hipStream_t stream) {
    const float* feat   = (const float*)d_in[0];
    const int*   src    = (const int*)  d_in[1];
    const int*   dst    = (const int*)  d_in[2];
    const int*   et     = (const int*)  d_in[3];
    const float* norm   = (const float*)d_in[4];
    const float* weight = (const float*)d_in[5];
    const float* w_comp = (const float*)d_in[6];
    const float* h_bias = (const float*)d_in[7];
    const float* loop_w = (const float*)d_in[8];
    float* out = (float*)d_out;

    const size_t needA = (size_t)NNODES * 8 * 64 * sizeof(__hip_bfloat16);  // 102.4 MB
    const size_t needB = (size_t)NNODES * 4 * 64 * sizeof(__hip_bfloat16);  //  51.2 MB

    const dim3 gridP(NNODES / 32);   // 3125 (100000 % 32 == 0)

    if (ws_size >= needA) {
        __hip_bfloat16* wfeat = (__hip_bfloat16*)d_ws;
        hipLaunchKernelGGL((rgcn_proj_kernel<0>), gridP, dim3(256), 0, stream,
                           feat, weight, w_comp, h_bias, loop_w, wfeat, out);
        hipLaunchKernelGGL(rgcn_edge_a, dim3(2048), dim3(256), 0, stream,
                           src, dst, et, norm, wfeat, out);
    } else if (ws_size >= needB) {
        __hip_bfloat16* proj = (__hip_bfloat16*)d_ws;
        hipLaunchKernelGGL((rgcn_proj_kernel<1>), gridP, dim3(256), 0, stream,
                           feat, weight, w_comp, h_bias, loop_w, proj, out);
        hipLaunchKernelGGL(rgcn_edge_b, dim3(2048), dim3(256), 0, stream,
                           src, dst, et, norm, proj, w_comp, out);
    } else {
        hipLaunchKernelGGL((rgcn_proj_kernel<2>), gridP, dim3(256), 0, stream,
                           feat, weight, w_comp, h_bias, loop_w,
                           (__hip_bfloat16*)nullptr, out);
        hipLaunchKernelGGL(rgcn_edge_c, dim3(2048), dim3(256), 0, stream,
                           src, dst, et, norm, feat, weight, w_comp, out);
    }
}

// Round 3
// 508.204 us; speedup vs baseline: 1.0027x; 1.0027x over previous
//
#include <hip/hip_runtime.h>
#include <hip/hip_bf16.h>

// RGCN basis-decomposition forward, round 3.
//
// K_proj:  Wfeat[n][r][:] = feat[n] @ W_r (bf16 table in ws), W_r combined
//          in-register from basis projections; V staged in LDS as packed bf16x2.
//          Also initializes out[n] = h_bias + feat[n] @ loop_w.
// CSR path (ws permitting): build dst-CSR on device each call, then one wave
//          per dst node accumulates in registers -> single non-atomic out +=.
//          Replaces 102.4M f32 atomics (the round-2 bottleneck: 303G atomics/s
//          = fabric RMW ceiling, 400MB write-through) with ~3.2M cheap atomics.
// Fallback (ws too small): round-2 atomic edge kernel (proven correct).

constexpr int NNODES = 100000;
constexpr int NEDGES = 1600000;

// ---- workspace layout (bytes) ----
constexpr size_t WF_BYTES = (size_t)NNODES * 512 * 2;        // 102,400,000
constexpr size_t CNT_OFF  = WF_BYTES;                        // counts int[N]
constexpr size_t TOT_OFF  = CNT_OFF + (size_t)NNODES * 4;    // total  int[1]
constexpr size_t OFFA_OFF = TOT_OFF + 256;                   // off    int[N]
constexpr size_t CUR_OFF  = OFFA_OFF + (size_t)NNODES * 4;   // cursor int[N]
constexpr size_t EID_OFF  = CUR_OFF + (size_t)NNODES * 4;    // eids   int[E]
constexpr size_t WS_NEED  = EID_OFF + (size_t)NEDGES * 4;    // 110,000,256

// ---------------------------------------------------------------------------
// K_proj: 32 nodes/block (4 waves x 8 nodes), lane = output column.
// LDS: feat tile 8KB + 5 matrices packed bf16x2 40KB = 48KB static.
// PATH: 0 -> write Wfeat[N][8][64]; 1 -> write proj[N][4][64]; 2 -> out only.
// ---------------------------------------------------------------------------
template <int PATH>
__global__ __launch_bounds__(256)
void rgcn_proj(const float* __restrict__ feat,
               const float* __restrict__ weight,   // [4][64][64]
               const float* __restrict__ w_comp,   // [8][4]
               const float* __restrict__ h_bias,   // [64]
               const float* __restrict__ loop_w,   // [64][64]
               __hip_bfloat16* __restrict__ table,
               float* __restrict__ out)            // [N][64]
{
    __shared__ float featl[32 * 64];           // 8 KB
    __shared__ unsigned int Vp[5 * 32 * 64];   // 40 KB: [m][i2][o], lo=even i

    const int t = threadIdx.x;
    const int nbase = blockIdx.x * 32;
    constexpr int NM = (PATH == 2) ? 1 : 5;

    {   // stage feat tile (coalesced float4)
        const float4* fsrc = (const float4*)(feat + (size_t)nbase * 64);
        float4* fdst = (float4*)featl;
        fdst[t] = fsrc[t];
        fdst[t + 256] = fsrc[t + 256];
    }
    // stage V matrices packed: Vp[m*2048 + i2*64 + o] = (bf16(V[2i2][o]) | bf16(V[2i2+1][o])<<16)
    for (int m = 0; m < NM; ++m) {
        const float* Wm = (PATH == 2) ? loop_w
                        : ((m < 4) ? (weight + m * 4096) : loop_w);
        #pragma unroll
        for (int kk = 0; kk < 8; ++kk) {
            const int k = t + kk * 256;          // 0..2047
            const int i2 = k >> 6, o = k & 63;
            __hip_bfloat16 hlo = __float2bfloat16(Wm[(2 * i2) * 64 + o]);
            __hip_bfloat16 hhi = __float2bfloat16(Wm[(2 * i2 + 1) * 64 + o]);
            const unsigned int ulo = *reinterpret_cast<const unsigned short*>(&hlo);
            const unsigned int uhi = *reinterpret_cast<const unsigned short*>(&hhi);
            Vp[m * 2048 + k] = ulo | (uhi << 16);
        }
    }

    const int lane = t & 63;
    const int n0 = (t >> 6) * 8;
    const float bias = h_bias[lane];

    __syncthreads();

    float acc[8][NM];
    #pragma unroll
    for (int n = 0; n < 8; ++n)
        #pragma unroll
        for (int m = 0; m < NM; ++m)
            acc[n][m] = 0.0f;

    #pragma unroll 4
    for (int i2 = 0; i2 < 32; ++i2) {          // input features 2*i2, 2*i2+1
        float vlo[NM], vhi[NM];
        #pragma unroll
        for (int m = 0; m < NM; ++m) {
            const unsigned int v = Vp[m * 2048 + i2 * 64 + lane];  // conflict-free
            vlo[m] = __uint_as_float(v << 16);
            vhi[m] = __uint_as_float(v & 0xffff0000u);
        }
        #pragma unroll
        for (int n = 0; n < 8; ++n) {
            const float2 f2 = *(const float2*)&featl[(n0 + n) * 64 + 2 * i2];
            #pragma unroll
            for (int m = 0; m < NM; ++m) {
                acc[n][m] = fmaf(f2.x, vlo[m], acc[n][m]);
                acc[n][m] = fmaf(f2.y, vhi[m], acc[n][m]);
            }
        }
    }

    float wc[8][4];
    if (PATH == 0) {
        #pragma unroll
        for (int r = 0; r < 8; ++r)
            #pragma unroll
            for (int b = 0; b < 4; ++b)
                wc[r][b] = w_comp[r * 4 + b];
    }

    #pragma unroll
    for (int n = 0; n < 8; ++n) {
        const size_t gn = (size_t)(nbase + n0 + n);
        out[gn * 64 + lane] = bias + acc[n][NM - 1];   // bias + self-loop
        if (PATH == 0) {
            #pragma unroll
            for (int r = 0; r < 8; ++r) {
                const float w = fmaf(wc[r][0], acc[n][0],
                                fmaf(wc[r][1], acc[n][1],
                                fmaf(wc[r][2], acc[n][2],
                                     wc[r][3] * acc[n][3])));
                table[gn * 512 + (size_t)r * 64 + lane] = __float2bfloat16(w);
            }
        } else if (PATH == 1) {
            #pragma unroll
            for (int b = 0; b < 4; ++b)
                table[gn * 256 + (size_t)b * 64 + lane] = __float2bfloat16(acc[n][b]);
        }
    }
}

// ---------------------------------------------------------------------------
// CSR build
// ---------------------------------------------------------------------------
__global__ __launch_bounds__(256)
void k_hist(const int* __restrict__ dst, int* __restrict__ counts)
{
    const int i = blockIdx.x * blockDim.x + threadIdx.x;
    const int stride = gridDim.x * blockDim.x;
    for (int e = i; e < NEDGES; e += stride)
        atomicAdd(&counts[dst[e]], 1);
}

__global__ __launch_bounds__(256)
void k_alloc(const int* __restrict__ counts, int* __restrict__ off,
             int* __restrict__ cursor, int* __restrict__ total)
{
    const int lane = threadIdx.x & 63;
    const int wid = (int)((blockIdx.x * blockDim.x + threadIdx.x) >> 6);
    const int nwaves = (int)((gridDim.x * blockDim.x) >> 6);

    for (int base = wid * 64; base < NNODES; base += nwaves * 64) {
        const int n = base + lane;
        const int deg = (n < NNODES) ? counts[n] : 0;
        int incl = deg;
        #pragma unroll
        for (int d = 1; d < 64; d <<= 1) {
            const int v = __shfl_up(incl, d);
            if (lane >= d) incl += v;
        }
        const int tot = __shfl(incl, 63);
        int basealloc = 0;
        if (lane == 63) basealloc = atomicAdd(total, tot);
        basealloc = __shfl(basealloc, 63);
        const int start = basealloc + incl - deg;
        if (n < NNODES) { off[n] = start; cursor[n] = start; }
    }
}

__global__ __launch_bounds__(256)
void k_scatter(const int* __restrict__ dst, int* __restrict__ cursor,
               int* __restrict__ eids)
{
    const int i = blockIdx.x * blockDim.x + threadIdx.x;
    const int stride = gridDim.x * blockDim.x;
    for (int e = i; e < NEDGES; e += stride) {
        const int d = dst[e];
        const int slot = atomicAdd(&cursor[d], 1);
        eids[slot] = e;
    }
}

// ---------------------------------------------------------------------------
// K_agg: one wave per dst node; register accumulation; single non-atomic +=.
// Unroll-4 over in-edges for memory-level parallelism on the 3-deep chain
// eid -> (src,et,norm) -> wfeat gather.
// ---------------------------------------------------------------------------
__global__ __launch_bounds__(256)
void k_agg(const int* __restrict__ off, const int* __restrict__ counts,
           const int* __restrict__ src, const int* __restrict__ et,
           const float* __restrict__ norm, const int* __restrict__ eids,
           const __hip_bfloat16* __restrict__ wfeat, float* __restrict__ out)
{
    const int lane = threadIdx.x & 63;
    const int wid = (int)((blockIdx.x * blockDim.x + threadIdx.x) >> 6);
    const int nwaves = (int)((gridDim.x * blockDim.x) >> 6);

    for (int n = wid; n < NNODES; n += nwaves) {
        const int start = off[n];
        const int deg = counts[n];
        float acc = 0.0f;
        int j = 0;
        for (; j + 4 <= deg; j += 4) {
            const int e0 = eids[start + j];
            const int e1 = eids[start + j + 1];
            const int e2 = eids[start + j + 2];
            const int e3 = eids[start + j + 3];
            const int s0 = src[e0], s1 = src[e1], s2 = src[e2], s3 = src[e3];
            const int r0 = et[e0],  r1 = et[e1],  r2 = et[e2],  r3 = et[e3];
            const float m0 = norm[e0], m1 = norm[e1], m2 = norm[e2], m3 = norm[e3];
            const float w0 = __bfloat162float(wfeat[(size_t)s0 * 512 + r0 * 64 + lane]);
            const float w1 = __bfloat162float(wfeat[(size_t)s1 * 512 + r1 * 64 + lane]);
            const float w2 = __bfloat162float(wfeat[(size_t)s2 * 512 + r2 * 64 + lane]);
            const float w3 = __bfloat162float(wfeat[(size_t)s3 * 512 + r3 * 64 + lane]);
            acc = fmaf(m0, w0, acc);
            acc = fmaf(m1, w1, acc);
            acc = fmaf(m2, w2, acc);
            acc = fmaf(m3, w3, acc);
        }
        for (; j < deg; ++j) {
            const int e = eids[start + j];
            const int s = src[e];
            const int r = et[e];
            const float m = norm[e];
            acc = fmaf(m, __bfloat162float(wfeat[(size_t)s * 512 + r * 64 + lane]), acc);
        }
        out[(size_t)n * 64 + lane] += acc;   // this wave exclusively owns node n
    }
}

// ---------------------------------------------------------------------------
// Fallback: round-2 atomic edge kernels (proven correct).
// ---------------------------------------------------------------------------
__global__ __launch_bounds__(256)
void rgcn_edge_a(const int* __restrict__ src, const int* __restrict__ dst,
                 const int* __restrict__ et, const float* __restrict__ norm,
                 const __hip_bfloat16* __restrict__ wfeat,
                 float* __restrict__ out)
{
    const int lane = threadIdx.x & 63;
    const int wid  = (int)((blockIdx.x * blockDim.x + threadIdx.x) >> 6);
    const int nw   = (int)((gridDim.x * blockDim.x) >> 6);
    for (int e = wid; e < NEDGES; e += nw) {
        const int   s  = src[e];
        const int   d  = dst[e];
        const int   r  = et[e];
        const float nm = norm[e];
        const float w  = __bfloat162float(wfeat[(size_t)s * 512 + (size_t)r * 64 + lane]);
        atomicAdd(out + (size_t)d * 64 + lane, w * nm);
    }
}

__global__ __launch_bounds__(256)
void rgcn_edge_b(const int* __restrict__ src, const int* __restrict__ dst,
                 const int* __restrict__ et, const float* __restrict__ norm,
                 const __hip_bfloat16* __restrict__ proj,
                 const float* __restrict__ w_comp,
                 float* __restrict__ out)
{
    const int lane = threadIdx.x & 63;
    const int wid  = (int)((blockIdx.x * blockDim.x + threadIdx.x) >> 6);
    const int nw   = (int)((gridDim.x * blockDim.x) >> 6);
    for (int e = wid; e < NEDGES; e += nw) {
        const int   s  = src[e];
        const int   d  = dst[e];
        const int   r  = et[e];
        const float nm = norm[e];
        const __hip_bfloat16* p = proj + (size_t)s * 256;
        float m = w_comp[r * 4 + 0] * __bfloat162float(p[lane]);
        m = fmaf(w_comp[r * 4 + 1], __bfloat162float(p[ 64 + lane]), m);
        m = fmaf(w_comp[r * 4 + 2], __bfloat162float(p[128 + lane]), m);
        m = fmaf(w_comp[r * 4 + 3], __bfloat162float(p[192 + lane]), m);
        atomicAdd(out + (size_t)d * 64 + lane, m * nm);
    }
}

__global__ __launch_bounds__(256)
void rgcn_edge_c(const int* __restrict__ src, const int* __restrict__ dst,
                 const int* __restrict__ et, const float* __restrict__ norm,
                 const float* __restrict__ feat,
                 const float* __restrict__ weight,
                 const float* __restrict__ w_comp,
                 float* __restrict__ out)
{
    __shared__ __hip_bfloat16 Vl[4 * 64 * 64];  // 32 KB
    const int t = threadIdx.x;
    #pragma unroll
    for (int k = 0; k < 64; ++k)
        Vl[t + k * 256] = __float2bfloat16(weight[t + k * 256]);
    __syncthreads();

    const int lane = t & 63;
    const int wid  = (int)((blockIdx.x * blockDim.x + t) >> 6);
    const int nw   = (int)((gridDim.x * blockDim.x) >> 6);
    for (int e = wid; e < NEDGES; e += nw) {
        const int   s  = src[e];
        const int   d  = dst[e];
        const int   r  = et[e];
        const float nm = norm[e];
        const float wc0 = w_comp[r * 4 + 0], wc1 = w_comp[r * 4 + 1];
        const float wc2 = w_comp[r * 4 + 2], wc3 = w_comp[r * 4 + 3];
        const float f = feat[(size_t)s * 64 + lane];
        float acc = 0.0f;
        #pragma unroll 8
        for (int i = 0; i < 64; ++i) {
            const float fi = __shfl(f, i);
            float w =        wc0 * __bfloat162float(Vl[          i * 64 + lane]);
            w = fmaf(wc1, __bfloat162float(Vl[ 4096 + i * 64 + lane]), w);
            w = fmaf(wc2, __bfloat162float(Vl[ 8192 + i * 64 + lane]), w);
            w = fmaf(wc3, __bfloat162float(Vl[12288 + i * 64 + lane]), w);
            acc = fmaf(fi, w, acc);
        }
        atomicAdd(out + (size_t)d * 64 + lane, acc * nm);
    }
}

// ---------------------------------------------------------------------------
extern "C" void kernel_launch(void* const* d_in, const int* in_sizes, int n_in,
                              void* d_out, int out_size, void* d_ws, size_t ws_size,
                              hipStream_t stream) {
    const float* feat   = (const float*)d_in[0];
    const int*   src    = (const int*)  d_in[1];
    const int*   dst    = (const int*)  d_in[2];
    const int*   et     = (const int*)  d_in[3];
    const float* norm   = (const float*)d_in[4];
    const float* weight = (const float*)d_in[5];
    const float* w_comp = (const float*)d_in[6];
    const float* h_bias = (const float*)d_in[7];
    const float* loop_w = (const float*)d_in[8];
    float* out = (float*)d_out;
    char* ws = (char*)d_ws;

    const dim3 gridP(NNODES / 32);  // 3125

    if (ws_size >= WS_NEED) {
        // ---- CSR path ----
        __hip_bfloat16* wfeat = (__hip_bfloat16*)ws;
        int* counts = (int*)(ws + CNT_OFF);
        int* total  = (int*)(ws + TOT_OFF);
        int* off    = (int*)(ws + OFFA_OFF);
        int* cursor = (int*)(ws + CUR_OFF);
        int* eids   = (int*)(ws + EID_OFF);

        hipMemsetAsync(ws + CNT_OFF, 0, (size_t)NNODES * 4 + 256, stream);
        hipLaunchKernelGGL((rgcn_proj<0>), gridP, dim3(256), 0, stream,
                           feat, weight, w_comp, h_bias, loop_w, wfeat, out);
        hipLaunchKernelGGL(k_hist, dim3(1024), dim3(256), 0, stream, dst, counts);
        hipLaunchKernelGGL(k_alloc, dim3(391), dim3(256), 0, stream,
                           counts, off, cursor, total);
        hipLaunchKernelGGL(k_scatter, dim3(1024), dim3(256), 0, stream,
                           dst, cursor, eids);
        hipLaunchKernelGGL(k_agg, dim3(2048), dim3(256), 0, stream,
                           off, counts, src, et, norm, eids, wfeat, out);
    } else if (ws_size >= WF_BYTES) {
        __hip_bfloat16* wfeat = (__hip_bfloat16*)ws;
        hipLaunchKernelGGL((rgcn_proj<0>), gridP, dim3(256), 0, stream,
                           feat, weight, w_comp, h_bias, loop_w, wfeat, out);
        hipLaunchKernelGGL(rgcn_edge_a, dim3(2048), dim3(256), 0, stream,
                           src, dst, et, norm, wfeat, out);
    } else if (ws_size >= (size_t)NNODES * 256 * 2) {
        __hip_bfloat16* proj = (__hip_bfloat16*)ws;
        hipLaunchKernelGGL((rgcn_proj<1>), gridP, dim3(256), 0, stream,
                           feat, weight, w_comp, h_bias, loop_w, proj, out);
        hipLaunchKernelGGL(rgcn_edge_b, dim3(2048), dim3(256), 0, stream,
                           src, dst, et, norm, proj, w_comp, out);
    } else {
        hipLaunchKernelGGL((rgcn_proj<2>), gridP, dim3(256), 0, stream,
                           feat, weight, w_comp, h_bias, loop_w,
                           (__hip_bfloat16*)nullptr, out);
        hipLaunchKernelGGL(rgcn_edge_c, dim3(2048), dim3(256), 0, stream,
                           src, dst, et, norm, feat, weight, w_comp, out);
    }
}

// Round 5
// 458.987 us; speedup vs baseline: 1.1103x; 1.1072x over previous
//
#include <hip/hip_runtime.h>
#include <hip/hip_bf16.h>

// RGCN basis-decomposition forward, round 5 (= round 4 resubmitted after
// infra-only GPUAcquisitionTimeout; no HW data invalidated the design).
//
// K_proj:  Wfeat[n][r][:] = feat[n] @ W_r (bf16 table in ws); W_r combined
//          in-register from basis projections; V staged in LDS packed bf16x2.
//          Also writes out[n] = h_bias + feat[n] @ loop_w.
// K_link:  per-dst linked lists in ONE pass (replaces round-3's
//          hist+alloc+scatter whose scattered 4B stores cost 151us):
//          old = atomicExch(head[dst[e]], e); next[e] = old  (coalesced!).
// K_agg:   one wave per 8 dst nodes; walks 8 chains concurrently in
//          registers (8-way MLP on the uniform pointer chase); per step one
//          128B wfeat gather; single non-atomic out += per node.
// Fallbacks for smaller ws: round-2/3 proven atomic paths.

constexpr int NNODES = 100000;
constexpr int NEDGES = 1600000;

// ---- workspace layout (bytes); must stay <= 110,000,256 (proven size) ----
constexpr size_t WF_BYTES = (size_t)NNODES * 512 * 2;        // 102,400,000
constexpr size_t HEAD_OFF = WF_BYTES;                        // int[N] heads
constexpr size_t NEXT_OFF = HEAD_OFF + (size_t)NNODES * 4;   // int[E] next
constexpr size_t WS_NEED  = NEXT_OFF + (size_t)NEDGES * 4;   // 109,200,000

// ---------------------------------------------------------------------------
// K_proj: 32 nodes/block (4 waves x 8 nodes), lane = output column.
// LDS: feat tile 8KB + 5 matrices packed bf16x2 40KB = 48KB static.
// PATH: 0 -> write Wfeat[N][8][64]; 1 -> write proj[N][4][64]; 2 -> out only.
// ---------------------------------------------------------------------------
template <int PATH>
__global__ __launch_bounds__(256)
void rgcn_proj(const float* __restrict__ feat,
               const float* __restrict__ weight,   // [4][64][64]
               const float* __restrict__ w_comp,   // [8][4]
               const float* __restrict__ h_bias,   // [64]
               const float* __restrict__ loop_w,   // [64][64]
               __hip_bfloat16* __restrict__ table,
               float* __restrict__ out)            // [N][64]
{
    __shared__ float featl[32 * 64];           // 8 KB
    __shared__ unsigned int Vp[5 * 32 * 64];   // 40 KB: [m][i2][o]

    const int t = threadIdx.x;
    const int nbase = blockIdx.x * 32;
    constexpr int NM = (PATH == 2) ? 1 : 5;

    {   // stage feat tile (coalesced float4)
        const float4* fsrc = (const float4*)(feat + (size_t)nbase * 64);
        float4* fdst = (float4*)featl;
        fdst[t] = fsrc[t];
        fdst[t + 256] = fsrc[t + 256];
    }
    // stage V packed: Vp[m*2048 + i2*64 + o] = bf16(V[2i2][o]) | bf16(V[2i2+1][o])<<16
    for (int m = 0; m < NM; ++m) {
        const float* Wm = (PATH == 2) ? loop_w
                        : ((m < 4) ? (weight + m * 4096) : loop_w);
        #pragma unroll
        for (int kk = 0; kk < 8; ++kk) {
            const int k = t + kk * 256;          // 0..2047
            const int i2 = k >> 6, o = k & 63;
            __hip_bfloat16 hlo = __float2bfloat16(Wm[(2 * i2) * 64 + o]);
            __hip_bfloat16 hhi = __float2bfloat16(Wm[(2 * i2 + 1) * 64 + o]);
            const unsigned int ulo = *reinterpret_cast<const unsigned short*>(&hlo);
            const unsigned int uhi = *reinterpret_cast<const unsigned short*>(&hhi);
            Vp[m * 2048 + k] = ulo | (uhi << 16);
        }
    }

    const int lane = t & 63;
    const int n0 = (t >> 6) * 8;
    const float bias = h_bias[lane];

    __syncthreads();

    float acc[8][NM];
    #pragma unroll
    for (int n = 0; n < 8; ++n)
        #pragma unroll
        for (int m = 0; m < NM; ++m)
            acc[n][m] = 0.0f;

    #pragma unroll 4
    for (int i2 = 0; i2 < 32; ++i2) {
        float vlo[NM], vhi[NM];
        #pragma unroll
        for (int m = 0; m < NM; ++m) {
            const unsigned int v = Vp[m * 2048 + i2 * 64 + lane];  // conflict-free
            vlo[m] = __uint_as_float(v << 16);
            vhi[m] = __uint_as_float(v & 0xffff0000u);
        }
        #pragma unroll
        for (int n = 0; n < 8; ++n) {
            const float2 f2 = *(const float2*)&featl[(n0 + n) * 64 + 2 * i2];
            #pragma unroll
            for (int m = 0; m < NM; ++m) {
                acc[n][m] = fmaf(f2.x, vlo[m], acc[n][m]);
                acc[n][m] = fmaf(f2.y, vhi[m], acc[n][m]);
            }
        }
    }

    float wc[8][4];
    if (PATH == 0) {
        #pragma unroll
        for (int r = 0; r < 8; ++r)
            #pragma unroll
            for (int b = 0; b < 4; ++b)
                wc[r][b] = w_comp[r * 4 + b];
    }

    #pragma unroll
    for (int n = 0; n < 8; ++n) {
        const size_t gn = (size_t)(nbase + n0 + n);
        out[gn * 64 + lane] = bias + acc[n][NM - 1];   // bias + self-loop
        if (PATH == 0) {
            #pragma unroll
            for (int r = 0; r < 8; ++r) {
                const float w = fmaf(wc[r][0], acc[n][0],
                                fmaf(wc[r][1], acc[n][1],
                                fmaf(wc[r][2], acc[n][2],
                                     wc[r][3] * acc[n][3])));
                table[gn * 512 + (size_t)r * 64 + lane] = __float2bfloat16(w);
            }
        } else if (PATH == 1) {
            #pragma unroll
            for (int b = 0; b < 4; ++b)
                table[gn * 256 + (size_t)b * 64 + lane] = __float2bfloat16(acc[n][b]);
        }
    }
}

// ---------------------------------------------------------------------------
// K_link: build per-dst linked lists in one pass.
// next[e] write is COALESCED (thread e -> next[e]); only the 4B exchange on
// head[] is random (400KB region, L2-resident).
// ---------------------------------------------------------------------------
__global__ __launch_bounds__(256)
void k_link(const int* __restrict__ dst, int* __restrict__ head,
            int* __restrict__ next)
{
    const int i = blockIdx.x * blockDim.x + threadIdx.x;
    const int stride = gridDim.x * blockDim.x;
    for (int e = i; e < NEDGES; e += stride) {
        const int d = dst[e];
        const int old = atomicExch(&head[d], e);
        next[e] = old;
    }
}

// ---------------------------------------------------------------------------
// K_agg: one wave per 8 dst nodes; 8 concurrent register chain-walks.
// All chase/control state is wave-uniform (head/next loads are uniform), so
// branches are non-divergent; the 8 next-loads per iteration are independent
// -> 8-way MLP hides L2/L3 latency. Single non-atomic out += per node.
// ---------------------------------------------------------------------------
__global__ __launch_bounds__(256)
void k_agg(const int* __restrict__ head, const int* __restrict__ next,
           const int* __restrict__ src, const int* __restrict__ et,
           const float* __restrict__ norm,
           const __hip_bfloat16* __restrict__ wfeat,
           float* __restrict__ out)
{
    const int lane = threadIdx.x & 63;
    const int wid = (int)((blockIdx.x * blockDim.x + threadIdx.x) >> 6);
    const int n0 = wid * 8;   // grid sized so n0+7 <= NNODES-1 exactly

    int   e[8];
    float acc[8];
    #pragma unroll
    for (int k = 0; k < 8; ++k) {
        e[k] = head[n0 + k];
        acc[k] = 0.0f;
    }

    while (true) {
        bool progress = false;
        #pragma unroll
        for (int k = 0; k < 8; ++k) {
            const int ek = e[k];
            if (ek >= 0) {
                progress = true;
                const int   s = src[ek];
                const int   r = et[ek];
                const float m = norm[ek];
                const float w = __bfloat162float(
                    wfeat[(size_t)s * 512 + (size_t)r * 64 + lane]);
                acc[k] = fmaf(m, w, acc[k]);
                e[k] = next[ek];
            }
        }
        if (!progress) break;
    }

    #pragma unroll
    for (int k = 0; k < 8; ++k)
        out[(size_t)(n0 + k) * 64 + lane] += acc[k];
}

// ---------------------------------------------------------------------------
// Fallbacks (proven): atomic edge kernels.
// ---------------------------------------------------------------------------
__global__ __launch_bounds__(256)
void rgcn_edge_a(const int* __restrict__ src, const int* __restrict__ dst,
                 const int* __restrict__ et, const float* __restrict__ norm,
                 const __hip_bfloat16* __restrict__ wfeat,
                 float* __restrict__ out)
{
    const int lane = threadIdx.x & 63;
    const int wid  = (int)((blockIdx.x * blockDim.x + threadIdx.x) >> 6);
    const int nw   = (int)((gridDim.x * blockDim.x) >> 6);
    for (int e = wid; e < NEDGES; e += nw) {
        const int   s  = src[e];
        const int   d  = dst[e];
        const int   r  = et[e];
        const float nm = norm[e];
        const float w  = __bfloat162float(wfeat[(size_t)s * 512 + (size_t)r * 64 + lane]);
        atomicAdd(out + (size_t)d * 64 + lane, w * nm);
    }
}

__global__ __launch_bounds__(256)
void rgcn_edge_b(const int* __restrict__ src, const int* __restrict__ dst,
                 const int* __restrict__ et, const float* __restrict__ norm,
                 const __hip_bfloat16* __restrict__ proj,
                 const float* __restrict__ w_comp,
                 float* __restrict__ out)
{
    const int lane = threadIdx.x & 63;
    const int wid  = (int)((blockIdx.x * blockDim.x + threadIdx.x) >> 6);
    const int nw   = (int)((gridDim.x * blockDim.x) >> 6);
    for (int e = wid; e < NEDGES; e += nw) {
        const int   s  = src[e];
        const int   d  = dst[e];
        const int   r  = et[e];
        const float nm = norm[e];
        const __hip_bfloat16* p = proj + (size_t)s * 256;
        float m = w_comp[r * 4 + 0] * __bfloat162float(p[lane]);
        m = fmaf(w_comp[r * 4 + 1], __bfloat162float(p[ 64 + lane]), m);
        m = fmaf(w_comp[r * 4 + 2], __bfloat162float(p[128 + lane]), m);
        m = fmaf(w_comp[r * 4 + 3], __bfloat162float(p[192 + lane]), m);
        atomicAdd(out + (size_t)d * 64 + lane, m * nm);
    }
}

__global__ __launch_bounds__(256)
void rgcn_edge_c(const int* __restrict__ src, const int* __restrict__ dst,
                 const int* __restrict__ et, const float* __restrict__ norm,
                 const float* __restrict__ feat,
                 const float* __restrict__ weight,
                 const float* __restrict__ w_comp,
                 float* __restrict__ out)
{
    __shared__ __hip_bfloat16 Vl[4 * 64 * 64];  // 32 KB
    const int t = threadIdx.x;
    #pragma unroll
    for (int k = 0; k < 64; ++k)
        Vl[t + k * 256] = __float2bfloat16(weight[t + k * 256]);
    __syncthreads();

    const int lane = t & 63;
    const int wid  = (int)((blockIdx.x * blockDim.x + t) >> 6);
    const int nw   = (int)((gridDim.x * blockDim.x) >> 6);
    for (int e = wid; e < NEDGES; e += nw) {
        const int   s  = src[e];
        const int   d  = dst[e];
        const int   r  = et[e];
        const float nm = norm[e];
        const float wc0 = w_comp[r * 4 + 0], wc1 = w_comp[r * 4 + 1];
        const float wc2 = w_comp[r * 4 + 2], wc3 = w_comp[r * 4 + 3];
        const float f = feat[(size_t)s * 64 + lane];
        float acc = 0.0f;
        #pragma unroll 8
        for (int i = 0; i < 64; ++i) {
            const float fi = __shfl(f, i);
            float w =        wc0 * __bfloat162float(Vl[          i * 64 + lane]);
            w = fmaf(wc1, __bfloat162float(Vl[ 4096 + i * 64 + lane]), w);
            w = fmaf(wc2, __bfloat162float(Vl[ 8192 + i * 64 + lane]), w);
            w = fmaf(wc3, __bfloat162float(Vl[12288 + i * 64 + lane]), w);
            acc = fmaf(fi, w, acc);
        }
        atomicAdd(out + (size_t)d * 64 + lane, acc * nm);
    }
}

// ---------------------------------------------------------------------------
extern "C" void kernel_launch(void* const* d_in, const int* in_sizes, int n_in,
                              void* d_out, int out_size, void* d_ws, size_t ws_size,
                              hipStream_t stream) {
    const float* feat   = (const float*)d_in[0];
    const int*   src    = (const int*)  d_in[1];
    const int*   dst    = (const int*)  d_in[2];
    const int*   et     = (const int*)  d_in[3];
    const float* norm   = (const float*)d_in[4];
    const float* weight = (const float*)d_in[5];
    const float* w_comp = (const float*)d_in[6];
    const float* h_bias = (const float*)d_in[7];
    const float* loop_w = (const float*)d_in[8];
    float* out = (float*)d_out;
    char* ws = (char*)d_ws;

    const dim3 gridP(NNODES / 32);  // 3125

    if (ws_size >= WS_NEED) {
        // ---- linked-list path ----
        __hip_bfloat16* wfeat = (__hip_bfloat16*)ws;
        int* head = (int*)(ws + HEAD_OFF);
        int* next = (int*)(ws + NEXT_OFF);

        hipMemsetAsync(head, 0xFF, (size_t)NNODES * 4, stream);  // head = -1
        hipLaunchKernelGGL((rgcn_proj<0>), gridP, dim3(256), 0, stream,
                           feat, weight, w_comp, h_bias, loop_w, wfeat, out);
        hipLaunchKernelGGL(k_link, dim3(2048), dim3(256), 0, stream,
                           dst, head, next);
        hipLaunchKernelGGL(k_agg, dim3(NNODES / 32), dim3(256), 0, stream,
                           head, next, src, et, norm, wfeat, out);
    } else if (ws_size >= WF_BYTES) {
        __hip_bfloat16* wfeat = (__hip_bfloat16*)ws;
        hipLaunchKernelGGL((rgcn_proj<0>), gridP, dim3(256), 0, stream,
                           feat, weight, w_comp, h_bias, loop_w, wfeat, out);
        hipLaunchKernelGGL(rgcn_edge_a, dim3(2048), dim3(256), 0, stream,
                           src, dst, et, norm, wfeat, out);
    } else if (ws_size >= (size_t)NNODES * 256 * 2) {
        __hip_bfloat16* proj = (__hip_bfloat16*)ws;
        hipLaunchKernelGGL((rgcn_proj<1>), gridP, dim3(256), 0, stream,
                           feat, weight, w_comp, h_bias, loop_w, proj, out);
        hipLaunchKernelGGL(rgcn_edge_b, dim3(2048), dim3(256), 0, stream,
                           src, dst, et, norm, proj, w_comp, out);
    } else {
        hipLaunchKernelGGL((rgcn_proj<2>), gridP, dim3(256), 0, stream,
                           feat, weight, w_comp, h_bias, loop_w,
                           (__hip_bfloat16*)nullptr, out);
        hipLaunchKernelGGL(rgcn_edge_c, dim3(2048), dim3(256), 0, stream,
                           src, dst, et, norm, feat, weight, w_comp, out);
    }
}

// Round 6
// 432.942 us; speedup vs baseline: 1.1771x; 1.0602x over previous
//
#include <hip/hip_runtime.h>
#include <hip/hip_bf16.h>

// RGCN basis-decomposition forward, round 6.
//
// K_proj:  reverted to the EXACT round-2 structure (measured 172us there;
//          the round-3 packed-LDS rewrite regressed it to ~220us by residual
//          arithmetic). V/loop_w read from global (L1/L2-hot), feat tile in
//          8KB LDS. Writes Wfeat[n][r][:] bf16 + out = bias + feat@loop_w.
// K_link:  one pass; builds per-dst lists with PAYLOAD-EMBEDDED records:
//          rec[e] = {next, src*512+et*64, norm} (16B, coalesced store by e).
//          Round-5 evidence: k_agg's 412MB FETCH == 4 random payload lines
//          per edge; embedding collapses that to 1 line per edge.
// K_agg:   one wave per 8 dst nodes, 8 register chain-walks; per step ONE
//          uniform 16B rec load + one 128B wfeat gather; non-atomic out +=.
// ws branching keeps every proven path as fallback.

constexpr int NNODES = 100000;
constexpr int NEDGES = 1600000;

// ---- workspace layouts (bytes) ----
constexpr size_t WF_BYTES  = (size_t)NNODES * 512 * 2;         // 102,400,000
// embedded-record path:
constexpr size_t HEADE_OFF = WF_BYTES;                         // int[N]
constexpr size_t REC_OFF   = HEADE_OFF + (size_t)NNODES * 4;   // int4[E]
constexpr size_t WS_NEED_E = REC_OFF + (size_t)NEDGES * 16;    // 128,400,000
// round-5 split path (proven to fit):
constexpr size_t HEAD_OFF  = WF_BYTES;                         // int[N]
constexpr size_t NEXT_OFF  = HEAD_OFF + (size_t)NNODES * 4;    // int[E]
constexpr size_t WS_NEED   = NEXT_OFF + (size_t)NEDGES * 4;    // 109,200,000

// ---------------------------------------------------------------------------
// K_proj: EXACT round-2 structure. 32 nodes/block (4 waves x 8 nodes),
// lane = output column. feat tile in 8KB LDS; V + loop_w from global.
// PATH: 0 -> write Wfeat[N][8][64]; 1 -> write proj[N][4][64]; 2 -> out only.
// ---------------------------------------------------------------------------
template <int PATH>
__global__ __launch_bounds__(256)
void rgcn_proj(const float* __restrict__ feat,
               const float* __restrict__ weight,   // [4][64][64]
               const float* __restrict__ w_comp,   // [8][4]
               const float* __restrict__ h_bias,   // [64]
               const float* __restrict__ loop_w,   // [64][64]
               __hip_bfloat16* __restrict__ table,
               float* __restrict__ out)            // [N][64]
{
    __shared__ float featl[32 * 64];  // 8 KB

    const int t = threadIdx.x;
    const int nbase = blockIdx.x * 32;

    {   // stage feat tile, coalesced float4
        const float4* fsrc = (const float4*)(feat + (size_t)nbase * 64);
        float4* fdst = (float4*)featl;
        fdst[t] = fsrc[t];
        fdst[t + 256] = fsrc[t + 256];
    }

    const int lane = t & 63;
    const int n0 = (t >> 6) * 8;    // first node of this wave within block
    const float bias = h_bias[lane];

    __syncthreads();

    constexpr int NM = (PATH == 2) ? 1 : 5;   // 4 bases + loop, or loop only
    float acc[8][NM];
    #pragma unroll
    for (int n = 0; n < 8; ++n)
        #pragma unroll
        for (int m = 0; m < NM; ++m)
            acc[n][m] = 0.0f;

    #pragma unroll 4
    for (int i0 = 0; i0 < 64; i0 += 4) {
        float4 f4[8];
        #pragma unroll
        for (int n = 0; n < 8; ++n)   // LDS broadcast reads (uniform addr/wave)
            f4[n] = *(const float4*)&featl[(n0 + n) * 64 + i0];
        #pragma unroll
        for (int q = 0; q < 4; ++q) {
            const int i = i0 + q;
            float vv[NM];
            if (PATH < 2) {
                #pragma unroll
                for (int b = 0; b < 4; ++b)           // coalesced, L1/L2-hot
                    vv[b] = weight[b * 4096 + i * 64 + lane];
                vv[4] = loop_w[i * 64 + lane];
            } else {
                vv[0] = loop_w[i * 64 + lane];
            }
            #pragma unroll
            for (int n = 0; n < 8; ++n) {
                const float fv = (q == 0) ? f4[n].x : (q == 1) ? f4[n].y
                               : (q == 2) ? f4[n].z : f4[n].w;
                #pragma unroll
                for (int m = 0; m < NM; ++m)
                    acc[n][m] = fmaf(fv, vv[m], acc[n][m]);
            }
        }
    }

    float wc[8][4];
    if (PATH == 0) {
        #pragma unroll
        for (int r = 0; r < 8; ++r)
            #pragma unroll
            for (int b = 0; b < 4; ++b)
                wc[r][b] = w_comp[r * 4 + b];
    }

    #pragma unroll
    for (int n = 0; n < 8; ++n) {
        const size_t gn = (size_t)(nbase + n0 + n);
        out[gn * 64 + lane] = bias + acc[n][NM - 1];   // bias + self-loop
        if (PATH == 0) {
            #pragma unroll
            for (int r = 0; r < 8; ++r) {
                const float w = fmaf(wc[r][0], acc[n][0],
                                fmaf(wc[r][1], acc[n][1],
                                fmaf(wc[r][2], acc[n][2],
                                     wc[r][3] * acc[n][3])));
                table[gn * 512 + (size_t)r * 64 + lane] = __float2bfloat16(w);
            }
        } else if (PATH == 1) {
            #pragma unroll
            for (int b = 0; b < 4; ++b)
                table[gn * 256 + (size_t)b * 64 + lane] = __float2bfloat16(acc[n][b]);
        }
    }
}

// ---------------------------------------------------------------------------
// K_link_emb: one pass; payload-embedded records.
// rec[e] = {next, widx = src*512 + et*64, norm_bits, 0}; store is COALESCED.
// Only random op: 4B atomicExch into 400KB head[] (L2-resident, ~5us).
// ---------------------------------------------------------------------------
__global__ __launch_bounds__(256)
void k_link_emb(const int* __restrict__ src, const int* __restrict__ dst,
                const int* __restrict__ et, const float* __restrict__ norm,
                int* __restrict__ head, int4* __restrict__ rec)
{
    const int i = blockIdx.x * blockDim.x + threadIdx.x;
    const int stride = gridDim.x * blockDim.x;
    for (int e = i; e < NEDGES; e += stride) {
        const int d = dst[e];
        const int s = src[e];
        const int r = et[e];
        const float nm = norm[e];
        const int old = atomicExch(&head[d], e);
        rec[e] = make_int4(old, s * 512 + r * 64, __float_as_int(nm), 0);
    }
}

// ---------------------------------------------------------------------------
// K_agg_emb: one wave per 8 dst nodes; 8 concurrent register chain-walks.
// Per edge-step: ONE uniform 16B rec load (1 line, vs round-5's 4 random
// lines) + one 128B wfeat gather + fma. Single non-atomic out += per node.
// ---------------------------------------------------------------------------
__global__ __launch_bounds__(256)
void k_agg_emb(const int* __restrict__ head, const int4* __restrict__ rec,
               const __hip_bfloat16* __restrict__ wfeat,
               float* __restrict__ out)
{
    const int lane = threadIdx.x & 63;
    const int wid = (int)((blockIdx.x * blockDim.x + threadIdx.x) >> 6);
    const int n0 = wid * 8;

    int   e[8];
    float acc[8];
    #pragma unroll
    for (int k = 0; k < 8; ++k) {
        e[k] = head[n0 + k];
        acc[k] = 0.0f;
    }

    while (true) {
        bool progress = false;
        #pragma unroll
        for (int k = 0; k < 8; ++k) {
            const int ek = e[k];
            if (ek >= 0) {
                progress = true;
                const int4 R = rec[ek];
                const float w = __bfloat162float(wfeat[(size_t)R.y + lane]);
                acc[k] = fmaf(__int_as_float(R.z), w, acc[k]);
                e[k] = R.x;
            }
        }
        if (!progress) break;
    }

    #pragma unroll
    for (int k = 0; k < 8; ++k)
        out[(size_t)(n0 + k) * 64 + lane] += acc[k];
}

// ---------------------------------------------------------------------------
// Round-5 proven kernels (fallback when ws < 128.4MB).
// ---------------------------------------------------------------------------
__global__ __launch_bounds__(256)
void k_link(const int* __restrict__ dst, int* __restrict__ head,
            int* __restrict__ next)
{
    const int i = blockIdx.x * blockDim.x + threadIdx.x;
    const int stride = gridDim.x * blockDim.x;
    for (int e = i; e < NEDGES; e += stride) {
        const int d = dst[e];
        const int old = atomicExch(&head[d], e);
        next[e] = old;
    }
}

__global__ __launch_bounds__(256)
void k_agg(const int* __restrict__ head, const int* __restrict__ next,
           const int* __restrict__ src, const int* __restrict__ et,
           const float* __restrict__ norm,
           const __hip_bfloat16* __restrict__ wfeat,
           float* __restrict__ out)
{
    const int lane = threadIdx.x & 63;
    const int wid = (int)((blockIdx.x * blockDim.x + threadIdx.x) >> 6);
    const int n0 = wid * 8;

    int   e[8];
    float acc[8];
    #pragma unroll
    for (int k = 0; k < 8; ++k) {
        e[k] = head[n0 + k];
        acc[k] = 0.0f;
    }

    while (true) {
        bool progress = false;
        #pragma unroll
        for (int k = 0; k < 8; ++k) {
            const int ek = e[k];
            if (ek >= 0) {
                progress = true;
                const int   s = src[ek];
                const int   r = et[ek];
                const float m = norm[ek];
                const float w = __bfloat162float(
                    wfeat[(size_t)s * 512 + (size_t)r * 64 + lane]);
                acc[k] = fmaf(m, w, acc[k]);
                e[k] = next[ek];
            }
        }
        if (!progress) break;
    }

    #pragma unroll
    for (int k = 0; k < 8; ++k)
        out[(size_t)(n0 + k) * 64 + lane] += acc[k];
}

__global__ __launch_bounds__(256)
void rgcn_edge_a(const int* __restrict__ src, const int* __restrict__ dst,
                 const int* __restrict__ et, const float* __restrict__ norm,
                 const __hip_bfloat16* __restrict__ wfeat,
                 float* __restrict__ out)
{
    const int lane = threadIdx.x & 63;
    const int wid  = (int)((blockIdx.x * blockDim.x + threadIdx.x) >> 6);
    const int nw   = (int)((gridDim.x * blockDim.x) >> 6);
    for (int e = wid; e < NEDGES; e += nw) {
        const int   s  = src[e];
        const int   d  = dst[e];
        const int   r  = et[e];
        const float nm = norm[e];
        const float w  = __bfloat162float(wfeat[(size_t)s * 512 + (size_t)r * 64 + lane]);
        atomicAdd(out + (size_t)d * 64 + lane, w * nm);
    }
}

__global__ __launch_bounds__(256)
void rgcn_edge_b(const int* __restrict__ src, const int* __restrict__ dst,
                 const int* __restrict__ et, const float* __restrict__ norm,
                 const __hip_bfloat16* __restrict__ proj,
                 const float* __restrict__ w_comp,
                 float* __restrict__ out)
{
    const int lane = threadIdx.x & 63;
    const int wid  = (int)((blockIdx.x * blockDim.x + threadIdx.x) >> 6);
    const int nw   = (int)((gridDim.x * blockDim.x) >> 6);
    for (int e = wid; e < NEDGES; e += nw) {
        const int   s  = src[e];
        const int   d  = dst[e];
        const int   r  = et[e];
        const float nm = norm[e];
        const __hip_bfloat16* p = proj + (size_t)s * 256;
        float m = w_comp[r * 4 + 0] * __bfloat162float(p[lane]);
        m = fmaf(w_comp[r * 4 + 1], __bfloat162float(p[ 64 + lane]), m);
        m = fmaf(w_comp[r * 4 + 2], __bfloat162float(p[128 + lane]), m);
        m = fmaf(w_comp[r * 4 + 3], __bfloat162float(p[192 + lane]), m);
        atomicAdd(out + (size_t)d * 64 + lane, m * nm);
    }
}

__global__ __launch_bounds__(256)
void rgcn_edge_c(const int* __restrict__ src, const int* __restrict__ dst,
                 const int* __restrict__ et, const float* __restrict__ norm,
                 const float* __restrict__ feat,
                 const float* __restrict__ weight,
                 const float* __restrict__ w_comp,
                 float* __restrict__ out)
{
    __shared__ __hip_bfloat16 Vl[4 * 64 * 64];  // 32 KB
    const int t = threadIdx.x;
    #pragma unroll
    for (int k = 0; k < 64; ++k)
        Vl[t + k * 256] = __float2bfloat16(weight[t + k * 256]);
    __syncthreads();

    const int lane = t & 63;
    const int wid  = (int)((blockIdx.x * blockDim.x + t) >> 6);
    const int nw   = (int)((gridDim.x * blockDim.x) >> 6);
    for (int e = wid; e < NEDGES; e += nw) {
        const int   s  = src[e];
        const int   d  = dst[e];
        const int   r  = et[e];
        const float nm = norm[e];
        const float wc0 = w_comp[r * 4 + 0], wc1 = w_comp[r * 4 + 1];
        const float wc2 = w_comp[r * 4 + 2], wc3 = w_comp[r * 4 + 3];
        const float f = feat[(size_t)s * 64 + lane];
        float acc = 0.0f;
        #pragma unroll 8
        for (int i = 0; i < 64; ++i) {
            const float fi = __shfl(f, i);
            float w =        wc0 * __bfloat162float(Vl[          i * 64 + lane]);
            w = fmaf(wc1, __bfloat162float(Vl[ 4096 + i * 64 + lane]), w);
            w = fmaf(wc2, __bfloat162float(Vl[ 8192 + i * 64 + lane]), w);
            w = fmaf(wc3, __bfloat162float(Vl[12288 + i * 64 + lane]), w);
            acc = fmaf(fi, w, acc);
        }
        atomicAdd(out + (size_t)d * 64 + lane, acc * nm);
    }
}

// ---------------------------------------------------------------------------
extern "C" void kernel_launch(void* const* d_in, const int* in_sizes, int n_in,
                              void* d_out, int out_size, void* d_ws, size_t ws_size,
                              hipStream_t stream) {
    const float* feat   = (const float*)d_in[0];
    const int*   src    = (const int*)  d_in[1];
    const int*   dst    = (const int*)  d_in[2];
    const int*   et     = (const int*)  d_in[3];
    const float* norm   = (const float*)d_in[4];
    const float* weight = (const float*)d_in[5];
    const float* w_comp = (const float*)d_in[6];
    const float* h_bias = (const float*)d_in[7];
    const float* loop_w = (const float*)d_in[8];
    float* out = (float*)d_out;
    char* ws = (char*)d_ws;

    const dim3 gridP(NNODES / 32);  // 3125

    if (ws_size >= WS_NEED_E) {
        // ---- embedded-record linked-list path ----
        __hip_bfloat16* wfeat = (__hip_bfloat16*)ws;
        int*  head = (int*)(ws + HEADE_OFF);
        int4* rec  = (int4*)(ws + REC_OFF);

        hipMemsetAsync(head, 0xFF, (size_t)NNODES * 4, stream);  // head = -1
        hipLaunchKernelGGL(k_link_emb, dim3(2048), dim3(256), 0, stream,
                           src, dst, et, norm, head, rec);
        hipLaunchKernelGGL((rgcn_proj<0>), gridP, dim3(256), 0, stream,
                           feat, weight, w_comp, h_bias, loop_w, wfeat, out);
        hipLaunchKernelGGL(k_agg_emb, dim3(NNODES / 32), dim3(256), 0, stream,
                           head, rec, wfeat, out);
    } else if (ws_size >= WS_NEED) {
        // ---- round-5 proven path ----
        __hip_bfloat16* wfeat = (__hip_bfloat16*)ws;
        int* head = (int*)(ws + HEAD_OFF);
        int* next = (int*)(ws + NEXT_OFF);

        hipMemsetAsync(head, 0xFF, (size_t)NNODES * 4, stream);
        hipLaunchKernelGGL(k_link, dim3(2048), dim3(256), 0, stream,
                           dst, head, next);
        hipLaunchKernelGGL((rgcn_proj<0>), gridP, dim3(256), 0, stream,
                           feat, weight, w_comp, h_bias, loop_w, wfeat, out);
        hipLaunchKernelGGL(k_agg, dim3(NNODES / 32), dim3(256), 0, stream,
                           head, next, src, et, norm, wfeat, out);
    } else if (ws_size >= WF_BYTES) {
        __hip_bfloat16* wfeat = (__hip_bfloat16*)ws;
        hipLaunchKernelGGL((rgcn_proj<0>), gridP, dim3(256), 0, stream,
                           feat, weight, w_comp, h_bias, loop_w, wfeat, out);
        hipLaunchKernelGGL(rgcn_edge_a, dim3(2048), dim3(256), 0, stream,
                           src, dst, et, norm, wfeat, out);
    } else if (ws_size >= (size_t)NNODES * 256 * 2) {
        __hip_bfloat16* proj = (__hip_bfloat16*)ws;
        hipLaunchKernelGGL((rgcn_proj<1>), gridP, dim3(256), 0, stream,
                           feat, weight, w_comp, h_bias, loop_w, proj, out);
        hipLaunchKernelGGL(rgcn_edge_b, dim3(2048), dim3(256), 0, stream,
                           src, dst, et, norm, proj, w_comp, out);
    } else {
        hipLaunchKernelGGL((rgcn_proj<2>), gridP, dim3(256), 0, stream,
                           feat, weight, w_comp, h_bias, loop_w,
                           (__hip_bfloat16*)nullptr, out);
        hipLaunchKernelGGL(rgcn_edge_c, dim3(2048), dim3(256), 0, stream,
                           src, dst, et, norm, feat, weight, w_comp, out);
    }
}

// Round 7
// 348.150 us; speedup vs baseline: 1.4637x; 1.2436x over previous
//
#include <hip/hip_runtime.h>
#include <hip/hip_bf16.h>

// RGCN basis-decomposition forward, round 7.
//
// Change vs round 6 (ONLY k_agg_emb): batch-then-consume chain walk.
// Round-6 evidence: FETCH fell 412->198MB as predicted but dur only
// 224->190us at 1.2TB/s / 13% VALU -> latency-serialized. Cause: each
// unrolled slot consumed rec[e[k]] immediately, forcing a vmcnt wait
// before the next slot's load (8 serial latency chains per iteration).
// Fix: phase the iteration: [8 unconditional rec loads] -> [8 gathers]
// -> [8 fma+advance]. Dead chains clamp index to 0 (branchless loads).
//
// K_proj / K_link_emb / layout / grid: bit-identical to round 6 so the
// per-dispatch counters attribute the delta cleanly.

constexpr int NNODES = 100000;
constexpr int NEDGES = 1600000;

// ---- workspace layouts (bytes) ----
constexpr size_t WF_BYTES  = (size_t)NNODES * 512 * 2;         // 102,400,000
// embedded-record path:
constexpr size_t HEADE_OFF = WF_BYTES;                         // int[N]
constexpr size_t REC_OFF   = HEADE_OFF + (size_t)NNODES * 4;   // int4[E]
constexpr size_t WS_NEED_E = REC_OFF + (size_t)NEDGES * 16;    // 128,400,000
// round-5 split path:
constexpr size_t HEAD_OFF  = WF_BYTES;                         // int[N]
constexpr size_t NEXT_OFF  = HEAD_OFF + (size_t)NNODES * 4;    // int[E]
constexpr size_t WS_NEED   = NEXT_OFF + (size_t)NEDGES * 4;    // 109,200,000

// ---------------------------------------------------------------------------
// K_proj: unchanged from round 6.
// ---------------------------------------------------------------------------
template <int PATH>
__global__ __launch_bounds__(256)
void rgcn_proj(const float* __restrict__ feat,
               const float* __restrict__ weight,   // [4][64][64]
               const float* __restrict__ w_comp,   // [8][4]
               const float* __restrict__ h_bias,   // [64]
               const float* __restrict__ loop_w,   // [64][64]
               __hip_bfloat16* __restrict__ table,
               float* __restrict__ out)            // [N][64]
{
    __shared__ float featl[32 * 64];  // 8 KB

    const int t = threadIdx.x;
    const int nbase = blockIdx.x * 32;

    {   // stage feat tile, coalesced float4
        const float4* fsrc = (const float4*)(feat + (size_t)nbase * 64);
        float4* fdst = (float4*)featl;
        fdst[t] = fsrc[t];
        fdst[t + 256] = fsrc[t + 256];
    }

    const int lane = t & 63;
    const int n0 = (t >> 6) * 8;
    const float bias = h_bias[lane];

    __syncthreads();

    constexpr int NM = (PATH == 2) ? 1 : 5;
    float acc[8][NM];
    #pragma unroll
    for (int n = 0; n < 8; ++n)
        #pragma unroll
        for (int m = 0; m < NM; ++m)
            acc[n][m] = 0.0f;

    #pragma unroll 4
    for (int i0 = 0; i0 < 64; i0 += 4) {
        float4 f4[8];
        #pragma unroll
        for (int n = 0; n < 8; ++n)
            f4[n] = *(const float4*)&featl[(n0 + n) * 64 + i0];
        #pragma unroll
        for (int q = 0; q < 4; ++q) {
            const int i = i0 + q;
            float vv[NM];
            if (PATH < 2) {
                #pragma unroll
                for (int b = 0; b < 4; ++b)
                    vv[b] = weight[b * 4096 + i * 64 + lane];
                vv[4] = loop_w[i * 64 + lane];
            } else {
                vv[0] = loop_w[i * 64 + lane];
            }
            #pragma unroll
            for (int n = 0; n < 8; ++n) {
                const float fv = (q == 0) ? f4[n].x : (q == 1) ? f4[n].y
                               : (q == 2) ? f4[n].z : f4[n].w;
                #pragma unroll
                for (int m = 0; m < NM; ++m)
                    acc[n][m] = fmaf(fv, vv[m], acc[n][m]);
            }
        }
    }

    float wc[8][4];
    if (PATH == 0) {
        #pragma unroll
        for (int r = 0; r < 8; ++r)
            #pragma unroll
            for (int b = 0; b < 4; ++b)
                wc[r][b] = w_comp[r * 4 + b];
    }

    #pragma unroll
    for (int n = 0; n < 8; ++n) {
        const size_t gn = (size_t)(nbase + n0 + n);
        out[gn * 64 + lane] = bias + acc[n][NM - 1];
        if (PATH == 0) {
            #pragma unroll
            for (int r = 0; r < 8; ++r) {
                const float w = fmaf(wc[r][0], acc[n][0],
                                fmaf(wc[r][1], acc[n][1],
                                fmaf(wc[r][2], acc[n][2],
                                     wc[r][3] * acc[n][3])));
                table[gn * 512 + (size_t)r * 64 + lane] = __float2bfloat16(w);
            }
        } else if (PATH == 1) {
            #pragma unroll
            for (int b = 0; b < 4; ++b)
                table[gn * 256 + (size_t)b * 64 + lane] = __float2bfloat16(acc[n][b]);
        }
    }
}

// ---------------------------------------------------------------------------
// K_link_emb: unchanged from round 6.
// ---------------------------------------------------------------------------
__global__ __launch_bounds__(256)
void k_link_emb(const int* __restrict__ src, const int* __restrict__ dst,
                const int* __restrict__ et, const float* __restrict__ norm,
                int* __restrict__ head, int4* __restrict__ rec)
{
    const int i = blockIdx.x * blockDim.x + threadIdx.x;
    const int stride = gridDim.x * blockDim.x;
    for (int e = i; e < NEDGES; e += stride) {
        const int d = dst[e];
        const int s = src[e];
        const int r = et[e];
        const float nm = norm[e];
        const int old = atomicExch(&head[d], e);
        rec[e] = make_int4(old, s * 512 + r * 64, __float_as_int(nm), 0);
    }
}

// ---------------------------------------------------------------------------
// K_agg_emb round 7: batch-then-consume.
// Phase 1: 8 UNCONDITIONAL rec loads (dead chains clamp to rec[0]) -> the
//          compiler can issue all 8 back-to-back (no intervening uses).
// Phase 2: 8 wfeat gathers consuming R[k].y -> staggered vmcnt waits.
// Phase 3: fma + pointer advance (register-only).
// Critical path per iteration ~ L_rec + L_gather instead of 8 x L.
// ---------------------------------------------------------------------------
__global__ __launch_bounds__(256)
void k_agg_emb(const int* __restrict__ head, const int4* __restrict__ rec,
               const __hip_bfloat16* __restrict__ wfeat,
               float* __restrict__ out)
{
    const int lane = threadIdx.x & 63;
    const int wid = (int)((blockIdx.x * blockDim.x + threadIdx.x) >> 6);
    const int n0 = wid * 8;

    int   e[8];
    float acc[8];
    bool alive = false;
    #pragma unroll
    for (int k = 0; k < 8; ++k) {
        e[k] = head[n0 + k];
        acc[k] = 0.0f;
        alive = alive || (e[k] >= 0);
    }

    while (alive) {
        // phase 1: batched, unconditional rec loads
        int4 R[8];
        #pragma unroll
        for (int k = 0; k < 8; ++k) {
            const int idx = (e[k] >= 0) ? e[k] : 0;
            R[k] = rec[idx];
        }
        // phase 2: batched gathers (dead slots read rec[0]'s target: harmless)
        float w[8];
        #pragma unroll
        for (int k = 0; k < 8; ++k)
            w[k] = __bfloat162float(wfeat[(size_t)R[k].y + lane]);
        // phase 3: accumulate + advance
        alive = false;
        #pragma unroll
        for (int k = 0; k < 8; ++k) {
            if (e[k] >= 0) {
                acc[k] = fmaf(__int_as_float(R[k].z), w[k], acc[k]);
                e[k] = R[k].x;
            }
            alive = alive || (e[k] >= 0);
        }
    }

    #pragma unroll
    for (int k = 0; k < 8; ++k)
        out[(size_t)(n0 + k) * 64 + lane] += acc[k];
}

// ---------------------------------------------------------------------------
// Round-5 proven kernels (fallbacks).
// ---------------------------------------------------------------------------
__global__ __launch_bounds__(256)
void k_link(const int* __restrict__ dst, int* __restrict__ head,
            int* __restrict__ next)
{
    const int i = blockIdx.x * blockDim.x + threadIdx.x;
    const int stride = gridDim.x * blockDim.x;
    for (int e = i; e < NEDGES; e += stride) {
        const int d = dst[e];
        const int old = atomicExch(&head[d], e);
        next[e] = old;
    }
}

__global__ __launch_bounds__(256)
void k_agg(const int* __restrict__ head, const int* __restrict__ next,
           const int* __restrict__ src, const int* __restrict__ et,
           const float* __restrict__ norm,
           const __hip_bfloat16* __restrict__ wfeat,
           float* __restrict__ out)
{
    const int lane = threadIdx.x & 63;
    const int wid = (int)((blockIdx.x * blockDim.x + threadIdx.x) >> 6);
    const int n0 = wid * 8;

    int   e[8];
    float acc[8];
    #pragma unroll
    for (int k = 0; k < 8; ++k) {
        e[k] = head[n0 + k];
        acc[k] = 0.0f;
    }

    while (true) {
        bool progress = false;
        #pragma unroll
        for (int k = 0; k < 8; ++k) {
            const int ek = e[k];
            if (ek >= 0) {
                progress = true;
                const int   s = src[ek];
                const int   r = et[ek];
                const float m = norm[ek];
                const float w = __bfloat162float(
                    wfeat[(size_t)s * 512 + (size_t)r * 64 + lane]);
                acc[k] = fmaf(m, w, acc[k]);
                e[k] = next[ek];
            }
        }
        if (!progress) break;
    }

    #pragma unroll
    for (int k = 0; k < 8; ++k)
        out[(size_t)(n0 + k) * 64 + lane] += acc[k];
}

__global__ __launch_bounds__(256)
void rgcn_edge_a(const int* __restrict__ src, const int* __restrict__ dst,
                 const int* __restrict__ et, const float* __restrict__ norm,
                 const __hip_bfloat16* __restrict__ wfeat,
                 float* __restrict__ out)
{
    const int lane = threadIdx.x & 63;
    const int wid  = (int)((blockIdx.x * blockDim.x + threadIdx.x) >> 6);
    const int nw   = (int)((gridDim.x * blockDim.x) >> 6);
    for (int e = wid; e < NEDGES; e += nw) {
        const int   s  = src[e];
        const int   d  = dst[e];
        const int   r  = et[e];
        const float nm = norm[e];
        const float w  = __bfloat162float(wfeat[(size_t)s * 512 + (size_t)r * 64 + lane]);
        atomicAdd(out + (size_t)d * 64 + lane, w * nm);
    }
}

__global__ __launch_bounds__(256)
void rgcn_edge_b(const int* __restrict__ src, const int* __restrict__ dst,
                 const int* __restrict__ et, const float* __restrict__ norm,
                 const __hip_bfloat16* __restrict__ proj,
                 const float* __restrict__ w_comp,
                 float* __restrict__ out)
{
    const int lane = threadIdx.x & 63;
    const int wid  = (int)((blockIdx.x * blockDim.x + threadIdx.x) >> 6);
    const int nw   = (int)((gridDim.x * blockDim.x) >> 6);
    for (int e = wid; e < NEDGES; e += nw) {
        const int   s  = src[e];
        const int   d  = dst[e];
        const int   r  = et[e];
        const float nm = norm[e];
        const __hip_bfloat16* p = proj + (size_t)s * 256;
        float m = w_comp[r * 4 + 0] * __bfloat162float(p[lane]);
        m = fmaf(w_comp[r * 4 + 1], __bfloat162float(p[ 64 + lane]), m);
        m = fmaf(w_comp[r * 4 + 2], __bfloat162float(p[128 + lane]), m);
        m = fmaf(w_comp[r * 4 + 3], __bfloat162float(p[192 + lane]), m);
        atomicAdd(out + (size_t)d * 64 + lane, m * nm);
    }
}

__global__ __launch_bounds__(256)
void rgcn_edge_c(const int* __restrict__ src, const int* __restrict__ dst,
                 const int* __restrict__ et, const float* __restrict__ norm,
                 const float* __restrict__ feat,
                 const float* __restrict__ weight,
                 const float* __restrict__ w_comp,
                 float* __restrict__ out)
{
    __shared__ __hip_bfloat16 Vl[4 * 64 * 64];  // 32 KB
    const int t = threadIdx.x;
    #pragma unroll
    for (int k = 0; k < 64; ++k)
        Vl[t + k * 256] = __float2bfloat16(weight[t + k * 256]);
    __syncthreads();

    const int lane = t & 63;
    const int wid  = (int)((blockIdx.x * blockDim.x + t) >> 6);
    const int nw   = (int)((gridDim.x * blockDim.x) >> 6);
    for (int e = wid; e < NEDGES; e += nw) {
        const int   s  = src[e];
        const int   d  = dst[e];
        const int   r  = et[e];
        const float nm = norm[e];
        const float wc0 = w_comp[r * 4 + 0], wc1 = w_comp[r * 4 + 1];
        const float wc2 = w_comp[r * 4 + 2], wc3 = w_comp[r * 4 + 3];
        const float f = feat[(size_t)s * 64 + lane];
        float acc = 0.0f;
        #pragma unroll 8
        for (int i = 0; i < 64; ++i) {
            const float fi = __shfl(f, i);
            float w =        wc0 * __bfloat162float(Vl[          i * 64 + lane]);
            w = fmaf(wc1, __bfloat162float(Vl[ 4096 + i * 64 + lane]), w);
            w = fmaf(wc2, __bfloat162float(Vl[ 8192 + i * 64 + lane]), w);
            w = fmaf(wc3, __bfloat162float(Vl[12288 + i * 64 + lane]), w);
            acc = fmaf(fi, w, acc);
        }
        atomicAdd(out + (size_t)d * 64 + lane, acc * nm);
    }
}

// ---------------------------------------------------------------------------
extern "C" void kernel_launch(void* const* d_in, const int* in_sizes, int n_in,
                              void* d_out, int out_size, void* d_ws, size_t ws_size,
                              hipStream_t stream) {
    const float* feat   = (const float*)d_in[0];
    const int*   src    = (const int*)  d_in[1];
    const int*   dst    = (const int*)  d_in[2];
    const int*   et     = (const int*)  d_in[3];
    const float* norm   = (const float*)d_in[4];
    const float* weight = (const float*)d_in[5];
    const float* w_comp = (const float*)d_in[6];
    const float* h_bias = (const float*)d_in[7];
    const float* loop_w = (const float*)d_in[8];
    float* out = (float*)d_out;
    char* ws = (char*)d_ws;

    const dim3 gridP(NNODES / 32);  // 3125

    if (ws_size >= WS_NEED_E) {
        // ---- embedded-record linked-list path ----
        __hip_bfloat16* wfeat = (__hip_bfloat16*)ws;
        int*  head = (int*)(ws + HEADE_OFF);
        int4* rec  = (int4*)(ws + REC_OFF);

        hipMemsetAsync(head, 0xFF, (size_t)NNODES * 4, stream);  // head = -1
        hipLaunchKernelGGL(k_link_emb, dim3(2048), dim3(256), 0, stream,
                           src, dst, et, norm, head, rec);
        hipLaunchKernelGGL((rgcn_proj<0>), gridP, dim3(256), 0, stream,
                           feat, weight, w_comp, h_bias, loop_w, wfeat, out);
        hipLaunchKernelGGL(k_agg_emb, dim3(NNODES / 32), dim3(256), 0, stream,
                           head, rec, wfeat, out);
    } else if (ws_size >= WS_NEED) {
        // ---- round-5 proven path ----
        __hip_bfloat16* wfeat = (__hip_bfloat16*)ws;
        int* head = (int*)(ws + HEAD_OFF);
        int* next = (int*)(ws + NEXT_OFF);

        hipMemsetAsync(head, 0xFF, (size_t)NNODES * 4, stream);
        hipLaunchKernelGGL(k_link, dim3(2048), dim3(256), 0, stream,
                           dst, head, next);
        hipLaunchKernelGGL((rgcn_proj<0>), gridP, dim3(256), 0, stream,
                           feat, weight, w_comp, h_bias, loop_w, wfeat, out);
        hipLaunchKernelGGL(k_agg, dim3(NNODES / 32), dim3(256), 0, stream,
                           head, next, src, et, norm, wfeat, out);
    } else if (ws_size >= WF_BYTES) {
        __hip_bfloat16* wfeat = (__hip_bfloat16*)ws;
        hipLaunchKernelGGL((rgcn_proj<0>), gridP, dim3(256), 0, stream,
                           feat, weight, w_comp, h_bias, loop_w, wfeat, out);
        hipLaunchKernelGGL(rgcn_edge_a, dim3(2048), dim3(256), 0, stream,
                           src, dst, et, norm, wfeat, out);
    } else if (ws_size >= (size_t)NNODES * 256 * 2) {
        __hip_bfloat16* proj = (__hip_bfloat16*)ws;
        hipLaunchKernelGGL((rgcn_proj<1>), gridP, dim3(256), 0, stream,
                           feat, weight, w_comp, h_bias, loop_w, proj, out);
        hipLaunchKernelGGL(rgcn_edge_b, dim3(2048), dim3(256), 0, stream,
                           src, dst, et, norm, proj, w_comp, out);
    } else {
        hipLaunchKernelGGL((rgcn_proj<2>), gridP, dim3(256), 0, stream,
                           feat, weight, w_comp, h_bias, loop_w,
                           (__hip_bfloat16*)nullptr, out);
        hipLaunchKernelGGL(rgcn_edge_c, dim3(2048), dim3(256), 0, stream,
                           src, dst, et, norm, feat, weight, w_comp, out);
    }
}

// Round 8
// 316.816 us; speedup vs baseline: 1.6085x; 1.0989x over previous
//
#include <hip/hip_runtime.h>
#include <hip/hip_bf16.h>

// RGCN basis-decomposition forward, round 8.
//
// Change vs round 7 (ONLY the projection): replace the scalar-FMA rgcn_proj
// (~172us by residual arithmetic, 4-6x above component floors -> latency
// bound) with an MFMA GEMM:
//   k_wcat:    Wcat_t[576][64] bf16 = concat(W_r = sum_b wc[r,b] V_b  (512),
//              loop_w (64)), transposed for B-fragment reads. ~2us.
//   proj_mfma: C[100K x 576] = feat_bf16 @ Wcat via mfma_f32_16x16x32_bf16.
//              Block: 32 nodes x 576 cols, 4 waves (2 Mfrag x 9 Nfrag each).
//              wfeat cols through padded-LDS transpose -> 1KB dwordx4 stores;
//              out cols direct + bias.
// k_link_emb / k_agg_emb: bit-identical to round 7 (agg at its gather floor).

constexpr int NNODES = 100000;
constexpr int NEDGES = 1600000;

// ---- workspace layouts (bytes) ----
constexpr size_t WF_BYTES  = (size_t)NNODES * 512 * 2;         // 102,400,000
constexpr size_t HEADE_OFF = WF_BYTES;                         // int[N]
constexpr size_t REC_OFF   = HEADE_OFF + (size_t)NNODES * 4;   // int4[E]
constexpr size_t WS_NEED_E = REC_OFF + (size_t)NEDGES * 16;    // 128,400,000
constexpr size_t WCAT_OFF  = WS_NEED_E;                        // bf16[576][64]
constexpr size_t WS_NEED_M = WCAT_OFF + (size_t)576 * 64 * 2;  // 128,473,728
// round-5 split path:
constexpr size_t HEAD_OFF  = WF_BYTES;
constexpr size_t NEXT_OFF  = HEAD_OFF + (size_t)NNODES * 4;
constexpr size_t WS_NEED   = NEXT_OFF + (size_t)NEDGES * 4;    // 109,200,000

typedef __attribute__((ext_vector_type(8))) short short8v;  // 8 bf16 (4 VGPR)
typedef __attribute__((ext_vector_type(4))) float f32x4;    // MFMA acc

// ---------------------------------------------------------------------------
// k_wcat: Wcat_t[c][i] (c = output col 0..575, i = input feat 0..63), bf16.
// c < 512: r=c>>6, o=c&63 -> sum_b w_comp[r][b] * V_b[i][o]; else loop_w.
// ---------------------------------------------------------------------------
__global__ __launch_bounds__(256)
void k_wcat(const float* __restrict__ weight, const float* __restrict__ w_comp,
            const float* __restrict__ loop_w, __hip_bfloat16* __restrict__ wcat)
{
    const int idx = blockIdx.x * 256 + threadIdx.x;   // grid 144 -> 36864
    if (idx >= 576 * 64) return;
    const int c = idx >> 6, i = idx & 63;
    float v;
    if (c < 512) {
        const int r = c >> 6, o = c & 63;
        v = w_comp[r * 4 + 0] * weight[        i * 64 + o]
          + w_comp[r * 4 + 1] * weight[ 4096 + i * 64 + o]
          + w_comp[r * 4 + 2] * weight[ 8192 + i * 64 + o]
          + w_comp[r * 4 + 3] * weight[12288 + i * 64 + o];
    } else {
        v = loop_w[i * 64 + (c - 512)];
    }
    wcat[(size_t)c * 64 + i] = __float2bfloat16(v);
}

// ---------------------------------------------------------------------------
// proj_mfma: 32 nodes/block, 4 waves; wave w owns cols w*144..w*144+143.
// mfma_f32_16x16x32_bf16 layouts (m89-verified C/D; standard A/B):
//   A[m][k]: m = lane&15, k = (lane>>4)*8 + j   (j=0..7)
//   B[k][n]: n = lane&15, k = (lane>>4)*8 + j
//   C[m][n]: n = lane&15, m = (lane>>4)*4 + q   (q=0..3)
// ---------------------------------------------------------------------------
__global__ __launch_bounds__(256)
void proj_mfma(const float* __restrict__ feat,
               const __hip_bfloat16* __restrict__ wcat,   // [576][64]
               const float* __restrict__ h_bias,
               __hip_bfloat16* __restrict__ wfeat,        // [N][512]
               float* __restrict__ out)                   // [N][64]
{
    __shared__ __hip_bfloat16 Alds[32 * 72];    // A tile, +8 pad (4.6KB)
    __shared__ __hip_bfloat16 Clds[32 * 520];   // wfeat cols, +8 pad (33.3KB)

    const int t = threadIdx.x;
    const int lane = t & 63;
    const int wv = t >> 6;            // 0..3
    const int nbase = blockIdx.x * 32;

    // ---- stage feat tile (32x64 f32 -> bf16 LDS), coalesced float4 ----
    {
        const float4* fsrc = (const float4*)(feat + (size_t)nbase * 64);
        #pragma unroll
        for (int kk = 0; kk < 2; ++kk) {
            const int idx = t + kk * 256;          // 0..511 float4s
            const float4 f = fsrc[idx];
            const int row = idx >> 4;              // 16 float4 per 64-f row
            const int c4  = (idx & 15) * 4;
            __hip_bfloat16* p = &Alds[row * 72 + c4];
            p[0] = __float2bfloat16(f.x);
            p[1] = __float2bfloat16(f.y);
            p[2] = __float2bfloat16(f.z);
            p[3] = __float2bfloat16(f.w);
        }
    }
    __syncthreads();

    const int colbase = wv * 144;
    const int lr = lane & 15;
    const int lg = lane >> 4;

    f32x4 acc[2][9];
    #pragma unroll
    for (int mf = 0; mf < 2; ++mf)
        #pragma unroll
        for (int nf = 0; nf < 9; ++nf)
            acc[mf][nf] = (f32x4){0.f, 0.f, 0.f, 0.f};

    #pragma unroll
    for (int ks = 0; ks < 2; ++ks) {
        short8v a[2];
        #pragma unroll
        for (int mf = 0; mf < 2; ++mf)
            a[mf] = *(const short8v*)&Alds[(mf * 16 + lr) * 72 + ks * 32 + lg * 8];
        short8v b[9];
        #pragma unroll
        for (int nf = 0; nf < 9; ++nf) {
            const int col = colbase + nf * 16 + lr;
            b[nf] = *(const short8v*)&wcat[(size_t)col * 64 + ks * 32 + lg * 8];
        }
        #pragma unroll
        for (int mf = 0; mf < 2; ++mf)
            #pragma unroll
            for (int nf = 0; nf < 9; ++nf)
                acc[mf][nf] = __builtin_amdgcn_mfma_f32_16x16x32_bf16(
                    a[mf], b[nf], acc[mf][nf], 0, 0, 0);
    }

    // ---- epilogue: wfeat cols -> Clds (transpose), out cols -> direct ----
    #pragma unroll
    for (int mf = 0; mf < 2; ++mf) {
        #pragma unroll
        for (int nf = 0; nf < 9; ++nf) {
            const int gc = colbase + nf * 16 + lr;   // 0..575, frag-uniform <512
            const int mrow = mf * 16 + lg * 4;
            if (gc < 512) {
                #pragma unroll
                for (int q = 0; q < 4; ++q)
                    Clds[(mrow + q) * 520 + gc] = __float2bfloat16(acc[mf][nf][q]);
            } else {
                const int o = gc - 512;
                const float bias = h_bias[o];
                #pragma unroll
                for (int q = 0; q < 4; ++q)
                    out[(size_t)(nbase + mrow + q) * 64 + o] = bias + acc[mf][nf][q];
            }
        }
    }
    __syncthreads();

    // coalesced wfeat store: one node row (1KB) per wave per pass
    #pragma unroll
    for (int p = 0; p < 8; ++p) {
        const int node = p * 4 + wv;
        const uint4 v = *(const uint4*)&Clds[node * 520 + lane * 8];
        *(uint4*)((char*)(wfeat + (size_t)(nbase + node) * 512) + lane * 16) = v;
    }
}

// ---------------------------------------------------------------------------
// K_link_emb: unchanged from round 7.
// ---------------------------------------------------------------------------
__global__ __launch_bounds__(256)
void k_link_emb(const int* __restrict__ src, const int* __restrict__ dst,
                const int* __restrict__ et, const float* __restrict__ norm,
                int* __restrict__ head, int4* __restrict__ rec)
{
    const int i = blockIdx.x * blockDim.x + threadIdx.x;
    const int stride = gridDim.x * blockDim.x;
    for (int e = i; e < NEDGES; e += stride) {
        const int d = dst[e];
        const int s = src[e];
        const int r = et[e];
        const float nm = norm[e];
        const int old = atomicExch(&head[d], e);
        rec[e] = make_int4(old, s * 512 + r * 64, __float_as_int(nm), 0);
    }
}

// ---------------------------------------------------------------------------
// K_agg_emb: unchanged from round 7 (batch-then-consume).
// ---------------------------------------------------------------------------
__global__ __launch_bounds__(256)
void k_agg_emb(const int* __restrict__ head, const int4* __restrict__ rec,
               const __hip_bfloat16* __restrict__ wfeat,
               float* __restrict__ out)
{
    const int lane = threadIdx.x & 63;
    const int wid = (int)((blockIdx.x * blockDim.x + threadIdx.x) >> 6);
    const int n0 = wid * 8;

    int   e[8];
    float acc[8];
    bool alive = false;
    #pragma unroll
    for (int k = 0; k < 8; ++k) {
        e[k] = head[n0 + k];
        acc[k] = 0.0f;
        alive = alive || (e[k] >= 0);
    }

    while (alive) {
        int4 R[8];
        #pragma unroll
        for (int k = 0; k < 8; ++k) {
            const int idx = (e[k] >= 0) ? e[k] : 0;
            R[k] = rec[idx];
        }
        float w[8];
        #pragma unroll
        for (int k = 0; k < 8; ++k)
            w[k] = __bfloat162float(wfeat[(size_t)R[k].y + lane]);
        alive = false;
        #pragma unroll
        for (int k = 0; k < 8; ++k) {
            if (e[k] >= 0) {
                acc[k] = fmaf(__int_as_float(R[k].z), w[k], acc[k]);
                e[k] = R[k].x;
            }
            alive = alive || (e[k] >= 0);
        }
    }

    #pragma unroll
    for (int k = 0; k < 8; ++k)
        out[(size_t)(n0 + k) * 64 + lane] += acc[k];
}

// ---------------------------------------------------------------------------
// Fallback kernels (proven in earlier rounds).
// ---------------------------------------------------------------------------
template <int PATH>
__global__ __launch_bounds__(256)
void rgcn_proj(const float* __restrict__ feat,
               const float* __restrict__ weight,
               const float* __restrict__ w_comp,
               const float* __restrict__ h_bias,
               const float* __restrict__ loop_w,
               __hip_bfloat16* __restrict__ table,
               float* __restrict__ out)
{
    __shared__ float featl[32 * 64];

    const int t = threadIdx.x;
    const int nbase = blockIdx.x * 32;

    {
        const float4* fsrc = (const float4*)(feat + (size_t)nbase * 64);
        float4* fdst = (float4*)featl;
        fdst[t] = fsrc[t];
        fdst[t + 256] = fsrc[t + 256];
    }

    const int lane = t & 63;
    const int n0 = (t >> 6) * 8;
    const float bias = h_bias[lane];

    __syncthreads();

    constexpr int NM = (PATH == 2) ? 1 : 5;
    float acc[8][NM];
    #pragma unroll
    for (int n = 0; n < 8; ++n)
        #pragma unroll
        for (int m = 0; m < NM; ++m)
            acc[n][m] = 0.0f;

    #pragma unroll 4
    for (int i0 = 0; i0 < 64; i0 += 4) {
        float4 f4[8];
        #pragma unroll
        for (int n = 0; n < 8; ++n)
            f4[n] = *(const float4*)&featl[(n0 + n) * 64 + i0];
        #pragma unroll
        for (int q = 0; q < 4; ++q) {
            const int i = i0 + q;
            float vv[NM];
            if (PATH < 2) {
                #pragma unroll
                for (int b = 0; b < 4; ++b)
                    vv[b] = weight[b * 4096 + i * 64 + lane];
                vv[4] = loop_w[i * 64 + lane];
            } else {
                vv[0] = loop_w[i * 64 + lane];
            }
            #pragma unroll
            for (int n = 0; n < 8; ++n) {
                const float fv = (q == 0) ? f4[n].x : (q == 1) ? f4[n].y
                               : (q == 2) ? f4[n].z : f4[n].w;
                #pragma unroll
                for (int m = 0; m < NM; ++m)
                    acc[n][m] = fmaf(fv, vv[m], acc[n][m]);
            }
        }
    }

    float wc[8][4];
    if (PATH == 0) {
        #pragma unroll
        for (int r = 0; r < 8; ++r)
            #pragma unroll
            for (int b = 0; b < 4; ++b)
                wc[r][b] = w_comp[r * 4 + b];
    }

    #pragma unroll
    for (int n = 0; n < 8; ++n) {
        const size_t gn = (size_t)(nbase + n0 + n);
        out[gn * 64 + lane] = bias + acc[n][NM - 1];
        if (PATH == 0) {
            #pragma unroll
            for (int r = 0; r < 8; ++r) {
                const float w = fmaf(wc[r][0], acc[n][0],
                                fmaf(wc[r][1], acc[n][1],
                                fmaf(wc[r][2], acc[n][2],
                                     wc[r][3] * acc[n][3])));
                table[gn * 512 + (size_t)r * 64 + lane] = __float2bfloat16(w);
            }
        } else if (PATH == 1) {
            #pragma unroll
            for (int b = 0; b < 4; ++b)
                table[gn * 256 + (size_t)b * 64 + lane] = __float2bfloat16(acc[n][b]);
        }
    }
}

__global__ __launch_bounds__(256)
void k_link(const int* __restrict__ dst, int* __restrict__ head,
            int* __restrict__ next)
{
    const int i = blockIdx.x * blockDim.x + threadIdx.x;
    const int stride = gridDim.x * blockDim.x;
    for (int e = i; e < NEDGES; e += stride) {
        const int d = dst[e];
        const int old = atomicExch(&head[d], e);
        next[e] = old;
    }
}

__global__ __launch_bounds__(256)
void k_agg(const int* __restrict__ head, const int* __restrict__ next,
           const int* __restrict__ src, const int* __restrict__ et,
           const float* __restrict__ norm,
           const __hip_bfloat16* __restrict__ wfeat,
           float* __restrict__ out)
{
    const int lane = threadIdx.x & 63;
    const int wid = (int)((blockIdx.x * blockDim.x + threadIdx.x) >> 6);
    const int n0 = wid * 8;

    int   e[8];
    float acc[8];
    #pragma unroll
    for (int k = 0; k < 8; ++k) {
        e[k] = head[n0 + k];
        acc[k] = 0.0f;
    }

    while (true) {
        bool progress = false;
        #pragma unroll
        for (int k = 0; k < 8; ++k) {
            const int ek = e[k];
            if (ek >= 0) {
                progress = true;
                const int   s = src[ek];
                const int   r = et[ek];
                const float m = norm[ek];
                const float w = __bfloat162float(
                    wfeat[(size_t)s * 512 + (size_t)r * 64 + lane]);
                acc[k] = fmaf(m, w, acc[k]);
                e[k] = next[ek];
            }
        }
        if (!progress) break;
    }

    #pragma unroll
    for (int k = 0; k < 8; ++k)
        out[(size_t)(n0 + k) * 64 + lane] += acc[k];
}

__global__ __launch_bounds__(256)
void rgcn_edge_a(const int* __restrict__ src, const int* __restrict__ dst,
                 const int* __restrict__ et, const float* __restrict__ norm,
                 const __hip_bfloat16* __restrict__ wfeat,
                 float* __restrict__ out)
{
    const int lane = threadIdx.x & 63;
    const int wid  = (int)((blockIdx.x * blockDim.x + threadIdx.x) >> 6);
    const int nw   = (int)((gridDim.x * blockDim.x) >> 6);
    for (int e = wid; e < NEDGES; e += nw) {
        const int   s  = src[e];
        const int   d  = dst[e];
        const int   r  = et[e];
        const float nm = norm[e];
        const float w  = __bfloat162float(wfeat[(size_t)s * 512 + (size_t)r * 64 + lane]);
        atomicAdd(out + (size_t)d * 64 + lane, w * nm);
    }
}

__global__ __launch_bounds__(256)
void rgcn_edge_b(const int* __restrict__ src, const int* __restrict__ dst,
                 const int* __restrict__ et, const float* __restrict__ norm,
                 const __hip_bfloat16* __restrict__ proj,
                 const float* __restrict__ w_comp,
                 float* __restrict__ out)
{
    const int lane = threadIdx.x & 63;
    const int wid  = (int)((blockIdx.x * blockDim.x + threadIdx.x) >> 6);
    const int nw   = (int)((gridDim.x * blockDim.x) >> 6);
    for (int e = wid; e < NEDGES; e += nw) {
        const int   s  = src[e];
        const int   d  = dst[e];
        const int   r  = et[e];
        const float nm = norm[e];
        const __hip_bfloat16* p = proj + (size_t)s * 256;
        float m = w_comp[r * 4 + 0] * __bfloat162float(p[lane]);
        m = fmaf(w_comp[r * 4 + 1], __bfloat162float(p[ 64 + lane]), m);
        m = fmaf(w_comp[r * 4 + 2], __bfloat162float(p[128 + lane]), m);
        m = fmaf(w_comp[r * 4 + 3], __bfloat162float(p[192 + lane]), m);
        atomicAdd(out + (size_t)d * 64 + lane, m * nm);
    }
}

__global__ __launch_bounds__(256)
void rgcn_edge_c(const int* __restrict__ src, const int* __restrict__ dst,
                 const int* __restrict__ et, const float* __restrict__ norm,
                 const float* __restrict__ feat,
                 const float* __restrict__ weight,
                 const float* __restrict__ w_comp,
                 float* __restrict__ out)
{
    __shared__ __hip_bfloat16 Vl[4 * 64 * 64];
    const int t = threadIdx.x;
    #pragma unroll
    for (int k = 0; k < 64; ++k)
        Vl[t + k * 256] = __float2bfloat16(weight[t + k * 256]);
    __syncthreads();

    const int lane = t & 63;
    const int wid  = (int)((blockIdx.x * blockDim.x + t) >> 6);
    const int nw   = (int)((gridDim.x * blockDim.x) >> 6);
    for (int e = wid; e < NEDGES; e += nw) {
        const int   s  = src[e];
        const int   d  = dst[e];
        const int   r  = et[e];
        const float nm = norm[e];
        const float wc0 = w_comp[r * 4 + 0], wc1 = w_comp[r * 4 + 1];
        const float wc2 = w_comp[r * 4 + 2], wc3 = w_comp[r * 4 + 3];
        const float f = feat[(size_t)s * 64 + lane];
        float acc = 0.0f;
        #pragma unroll 8
        for (int i = 0; i < 64; ++i) {
            const float fi = __shfl(f, i);
            float w =        wc0 * __bfloat162float(Vl[          i * 64 + lane]);
            w = fmaf(wc1, __bfloat162float(Vl[ 4096 + i * 64 + lane]), w);
            w = fmaf(wc2, __bfloat162float(Vl[ 8192 + i * 64 + lane]), w);
            w = fmaf(wc3, __bfloat162float(Vl[12288 + i * 64 + lane]), w);
            acc = fmaf(fi, w, acc);
        }
        atomicAdd(out + (size_t)d * 64 + lane, acc * nm);
    }
}

// ---------------------------------------------------------------------------
extern "C" void kernel_launch(void* const* d_in, const int* in_sizes, int n_in,
                              void* d_out, int out_size, void* d_ws, size_t ws_size,
                              hipStream_t stream) {
    const float* feat   = (const float*)d_in[0];
    const int*   src    = (const int*)  d_in[1];
    const int*   dst    = (const int*)  d_in[2];
    const int*   et     = (const int*)  d_in[3];
    const float* norm   = (const float*)d_in[4];
    const float* weight = (const float*)d_in[5];
    const float* w_comp = (const float*)d_in[6];
    const float* h_bias = (const float*)d_in[7];
    const float* loop_w = (const float*)d_in[8];
    float* out = (float*)d_out;
    char* ws = (char*)d_ws;

    const dim3 gridP(NNODES / 32);  // 3125

    if (ws_size >= WS_NEED_M) {
        // ---- MFMA proj + embedded-record linked-list path ----
        __hip_bfloat16* wfeat = (__hip_bfloat16*)ws;
        int*  head = (int*)(ws + HEADE_OFF);
        int4* rec  = (int4*)(ws + REC_OFF);
        __hip_bfloat16* wcat = (__hip_bfloat16*)(ws + WCAT_OFF);

        hipMemsetAsync(head, 0xFF, (size_t)NNODES * 4, stream);
        hipLaunchKernelGGL(k_wcat, dim3(144), dim3(256), 0, stream,
                           weight, w_comp, loop_w, wcat);
        hipLaunchKernelGGL(k_link_emb, dim3(2048), dim3(256), 0, stream,
                           src, dst, et, norm, head, rec);
        hipLaunchKernelGGL(proj_mfma, gridP, dim3(256), 0, stream,
                           feat, wcat, h_bias, wfeat, out);
        hipLaunchKernelGGL(k_agg_emb, dim3(NNODES / 32), dim3(256), 0, stream,
                           head, rec, wfeat, out);
    } else if (ws_size >= WS_NEED_E) {
        // ---- round-7 proven path ----
        __hip_bfloat16* wfeat = (__hip_bfloat16*)ws;
        int*  head = (int*)(ws + HEADE_OFF);
        int4* rec  = (int4*)(ws + REC_OFF);

        hipMemsetAsync(head, 0xFF, (size_t)NNODES * 4, stream);
        hipLaunchKernelGGL(k_link_emb, dim3(2048), dim3(256), 0, stream,
                           src, dst, et, norm, head, rec);
        hipLaunchKernelGGL((rgcn_proj<0>), gridP, dim3(256), 0, stream,
                           feat, weight, w_comp, h_bias, loop_w, wfeat, out);
        hipLaunchKernelGGL(k_agg_emb, dim3(NNODES / 32), dim3(256), 0, stream,
                           head, rec, wfeat, out);
    } else if (ws_size >= WS_NEED) {
        __hip_bfloat16* wfeat = (__hip_bfloat16*)ws;
        int* head = (int*)(ws + HEAD_OFF);
        int* next = (int*)(ws + NEXT_OFF);

        hipMemsetAsync(head, 0xFF, (size_t)NNODES * 4, stream);
        hipLaunchKernelGGL(k_link, dim3(2048), dim3(256), 0, stream,
                           dst, head, next);
        hipLaunchKernelGGL((rgcn_proj<0>), gridP, dim3(256), 0, stream,
                           feat, weight, w_comp, h_bias, loop_w, wfeat, out);
        hipLaunchKernelGGL(k_agg, dim3(NNODES / 32), dim3(256), 0, stream,
                           head, next, src, et, norm, wfeat, out);
    } else if (ws_size >= WF_BYTES) {
        __hip_bfloat16* wfeat = (__hip_bfloat16*)ws;
        hipLaunchKernelGGL((rgcn_proj<0>), gridP, dim3(256), 0, stream,
                           feat, weight, w_comp, h_bias, loop_w, wfeat, out);
        hipLaunchKernelGGL(rgcn_edge_a, dim3(2048), dim3(256), 0, stream,
                           src, dst, et, norm, wfeat, out);
    } else if (ws_size >= (size_t)NNODES * 256 * 2) {
        __hip_bfloat16* proj = (__hip_bfloat16*)ws;
        hipLaunchKernelGGL((rgcn_proj<1>), gridP, dim3(256), 0, stream,
                           feat, weight, w_comp, h_bias, loop_w, proj, out);
        hipLaunchKernelGGL(rgcn_edge_b, dim3(2048), dim3(256), 0, stream,
                           src, dst, et, norm, proj, w_comp, out);
    } else {
        hipLaunchKernelGGL((rgcn_proj<2>), gridP, dim3(256), 0, stream,
                           feat, weight, w_comp, h_bias, loop_w,
                           (__hip_bfloat16*)nullptr, out);
        hipLaunchKernelGGL(rgcn_edge_c, dim3(2048), dim3(256), 0, stream,
                           src, dst, et, norm, feat, weight, w_comp, out);
    }
}

// Round 9
// 289.389 us; speedup vs baseline: 1.7609x; 1.0948x over previous
//
#include <hip/hip_runtime.h>
#include <hip/hip_bf16.h>

// RGCN basis-decomposition forward, round 9.
//
// Change vs round 8 (structural, single change): fuse k_link_emb (~68us) and
// proj_mfma (~65us) into ONE kernel with interleaved block roles. They have
// no data dependency (edges->rec/head vs feat->wfeat); only k_agg_emb needs
// both. Single-stream launches serialized them; block-level fusion co-runs
// link's latency-bound atomics under proj's MFMA/LDS work.
// Role map (grid 4687): bid%3<2 -> proj tile (g*2+r in 0..3124);
//                       bid%3==2 -> link grid-stride (1562 blocks).
// k_wcat / memset precede (wcat + head init); k_agg_emb bit-identical.

constexpr int NNODES = 100000;
constexpr int NEDGES = 1600000;

// ---- workspace layouts (bytes) ----
constexpr size_t WF_BYTES  = (size_t)NNODES * 512 * 2;         // 102,400,000
constexpr size_t HEADE_OFF = WF_BYTES;                         // int[N]
constexpr size_t REC_OFF   = HEADE_OFF + (size_t)NNODES * 4;   // int4[E]
constexpr size_t WS_NEED_E = REC_OFF + (size_t)NEDGES * 16;    // 128,400,000
constexpr size_t WCAT_OFF  = WS_NEED_E;                        // bf16[576][64]
constexpr size_t WS_NEED_M = WCAT_OFF + (size_t)576 * 64 * 2;  // 128,473,728
// round-5 split path:
constexpr size_t HEAD_OFF  = WF_BYTES;
constexpr size_t NEXT_OFF  = HEAD_OFF + (size_t)NNODES * 4;
constexpr size_t WS_NEED   = NEXT_OFF + (size_t)NEDGES * 4;    // 109,200,000

typedef __attribute__((ext_vector_type(8))) short short8v;  // 8 bf16 (4 VGPR)
typedef __attribute__((ext_vector_type(4))) float f32x4;    // MFMA acc

// ---------------------------------------------------------------------------
// k_wcat: Wcat_t[c][i] (c = output col 0..575, i = input feat 0..63), bf16.
// ---------------------------------------------------------------------------
__global__ __launch_bounds__(256)
void k_wcat(const float* __restrict__ weight, const float* __restrict__ w_comp,
            const float* __restrict__ loop_w, __hip_bfloat16* __restrict__ wcat)
{
    const int idx = blockIdx.x * 256 + threadIdx.x;   // grid 144 -> 36864
    if (idx >= 576 * 64) return;
    const int c = idx >> 6, i = idx & 63;
    float v;
    if (c < 512) {
        const int r = c >> 6, o = c & 63;
        v = w_comp[r * 4 + 0] * weight[        i * 64 + o]
          + w_comp[r * 4 + 1] * weight[ 4096 + i * 64 + o]
          + w_comp[r * 4 + 2] * weight[ 8192 + i * 64 + o]
          + w_comp[r * 4 + 3] * weight[12288 + i * 64 + o];
    } else {
        v = loop_w[i * 64 + (c - 512)];
    }
    wcat[(size_t)c * 64 + i] = __float2bfloat16(v);
}

// ---------------------------------------------------------------------------
// k_fused: interleaved proj-MFMA + link-emb roles.
//   proj role: 32 nodes/block, 4 waves; wave w owns cols w*144..+143.
//     mfma_f32_16x16x32_bf16 layouts (m89-verified):
//       A[m][k]: m=lane&15, k=(lane>>4)*8+j ; B[k][n]: n=lane&15, same k
//       C[m][n]: n=lane&15, m=(lane>>4)*4+q
//   link role: rec[e] = {next, src*512+et*64, norm_bits, 0}; coalesced store;
//     only random op is 4B atomicExch into 400KB head[].
// ---------------------------------------------------------------------------
__global__ __launch_bounds__(256)
void k_fused(const float* __restrict__ feat,
             const __hip_bfloat16* __restrict__ wcat,   // [576][64]
             const float* __restrict__ h_bias,
             __hip_bfloat16* __restrict__ wfeat,        // [N][512]
             float* __restrict__ out,                   // [N][64]
             const int* __restrict__ src, const int* __restrict__ dst,
             const int* __restrict__ et, const float* __restrict__ norm,
             int* __restrict__ head, int4* __restrict__ rec)
{
    __shared__ __hip_bfloat16 Alds[32 * 72];    // A tile, +8 pad
    __shared__ __hip_bfloat16 Clds[32 * 520];   // wfeat cols, +8 pad

    const int bid = blockIdx.x;
    const int t = threadIdx.x;
    const int g = bid / 3;
    const int rrole = bid - g * 3;

    if (rrole == 2) {
        // ================= link role (1562 blocks) =================
        const int i = g * 256 + t;
        const int stride = 1562 * 256;
        for (int e = i; e < NEDGES; e += stride) {
            const int d = dst[e];
            const int s = src[e];
            const int rr = et[e];
            const float nm = norm[e];
            const int old = atomicExch(&head[d], e);
            rec[e] = make_int4(old, s * 512 + rr * 64, __float_as_int(nm), 0);
        }
        return;
    }

    // ================= proj role (3125 blocks) =================
    const int pidx = g * 2 + rrole;          // 0..3124
    const int lane = t & 63;
    const int wv = t >> 6;                   // 0..3
    const int nbase = pidx * 32;

    // ---- stage feat tile (32x64 f32 -> bf16 LDS), coalesced float4 ----
    {
        const float4* fsrc = (const float4*)(feat + (size_t)nbase * 64);
        #pragma unroll
        for (int kk = 0; kk < 2; ++kk) {
            const int idx = t + kk * 256;          // 0..511 float4s
            const float4 f = fsrc[idx];
            const int row = idx >> 4;
            const int c4  = (idx & 15) * 4;
            __hip_bfloat16* p = &Alds[row * 72 + c4];
            p[0] = __float2bfloat16(f.x);
            p[1] = __float2bfloat16(f.y);
            p[2] = __float2bfloat16(f.z);
            p[3] = __float2bfloat16(f.w);
        }
    }
    __syncthreads();

    const int colbase = wv * 144;
    const int lr = lane & 15;
    const int lg = lane >> 4;

    f32x4 acc[2][9];
    #pragma unroll
    for (int mf = 0; mf < 2; ++mf)
        #pragma unroll
        for (int nf = 0; nf < 9; ++nf)
            acc[mf][nf] = (f32x4){0.f, 0.f, 0.f, 0.f};

    #pragma unroll
    for (int ks = 0; ks < 2; ++ks) {
        short8v a[2];
        #pragma unroll
        for (int mf = 0; mf < 2; ++mf)
            a[mf] = *(const short8v*)&Alds[(mf * 16 + lr) * 72 + ks * 32 + lg * 8];
        short8v b[9];
        #pragma unroll
        for (int nf = 0; nf < 9; ++nf) {
            const int col = colbase + nf * 16 + lr;
            b[nf] = *(const short8v*)&wcat[(size_t)col * 64 + ks * 32 + lg * 8];
        }
        #pragma unroll
        for (int mf = 0; mf < 2; ++mf)
            #pragma unroll
            for (int nf = 0; nf < 9; ++nf)
                acc[mf][nf] = __builtin_amdgcn_mfma_f32_16x16x32_bf16(
                    a[mf], b[nf], acc[mf][nf], 0, 0, 0);
    }

    // ---- epilogue: wfeat cols -> Clds (transpose), out cols -> direct ----
    #pragma unroll
    for (int mf = 0; mf < 2; ++mf) {
        #pragma unroll
        for (int nf = 0; nf < 9; ++nf) {
            const int gc = colbase + nf * 16 + lr;
            const int mrow = mf * 16 + lg * 4;
            if (gc < 512) {
                #pragma unroll
                for (int q = 0; q < 4; ++q)
                    Clds[(mrow + q) * 520 + gc] = __float2bfloat16(acc[mf][nf][q]);
            } else {
                const int o = gc - 512;
                const float bias = h_bias[o];
                #pragma unroll
                for (int q = 0; q < 4; ++q)
                    out[(size_t)(nbase + mrow + q) * 64 + o] = bias + acc[mf][nf][q];
            }
        }
    }
    __syncthreads();

    // coalesced wfeat store: one node row (1KB) per wave per pass
    #pragma unroll
    for (int p = 0; p < 8; ++p) {
        const int node = p * 4 + wv;
        const uint4 v = *(const uint4*)&Clds[node * 520 + lane * 8];
        *(uint4*)((char*)(wfeat + (size_t)(nbase + node) * 512) + lane * 16) = v;
    }
}

// ---------------------------------------------------------------------------
// K_agg_emb: unchanged from round 7/8 (batch-then-consume).
// ---------------------------------------------------------------------------
__global__ __launch_bounds__(256)
void k_agg_emb(const int* __restrict__ head, const int4* __restrict__ rec,
               const __hip_bfloat16* __restrict__ wfeat,
               float* __restrict__ out)
{
    const int lane = threadIdx.x & 63;
    const int wid = (int)((blockIdx.x * blockDim.x + threadIdx.x) >> 6);
    const int n0 = wid * 8;

    int   e[8];
    float acc[8];
    bool alive = false;
    #pragma unroll
    for (int k = 0; k < 8; ++k) {
        e[k] = head[n0 + k];
        acc[k] = 0.0f;
        alive = alive || (e[k] >= 0);
    }

    while (alive) {
        int4 R[8];
        #pragma unroll
        for (int k = 0; k < 8; ++k) {
            const int idx = (e[k] >= 0) ? e[k] : 0;
            R[k] = rec[idx];
        }
        float w[8];
        #pragma unroll
        for (int k = 0; k < 8; ++k)
            w[k] = __bfloat162float(wfeat[(size_t)R[k].y + lane]);
        alive = false;
        #pragma unroll
        for (int k = 0; k < 8; ++k) {
            if (e[k] >= 0) {
                acc[k] = fmaf(__int_as_float(R[k].z), w[k], acc[k]);
                e[k] = R[k].x;
            }
            alive = alive || (e[k] >= 0);
        }
    }

    #pragma unroll
    for (int k = 0; k < 8; ++k)
        out[(size_t)(n0 + k) * 64 + lane] += acc[k];
}

// ---------------------------------------------------------------------------
// Fallback kernels (proven in earlier rounds).
// ---------------------------------------------------------------------------
__global__ __launch_bounds__(256)
void k_link_emb(const int* __restrict__ src, const int* __restrict__ dst,
                const int* __restrict__ et, const float* __restrict__ norm,
                int* __restrict__ head, int4* __restrict__ rec)
{
    const int i = blockIdx.x * blockDim.x + threadIdx.x;
    const int stride = gridDim.x * blockDim.x;
    for (int e = i; e < NEDGES; e += stride) {
        const int d = dst[e];
        const int s = src[e];
        const int r = et[e];
        const float nm = norm[e];
        const int old = atomicExch(&head[d], e);
        rec[e] = make_int4(old, s * 512 + r * 64, __float_as_int(nm), 0);
    }
}

template <int PATH>
__global__ __launch_bounds__(256)
void rgcn_proj(const float* __restrict__ feat,
               const float* __restrict__ weight,
               const float* __restrict__ w_comp,
               const float* __restrict__ h_bias,
               const float* __restrict__ loop_w,
               __hip_bfloat16* __restrict__ table,
               float* __restrict__ out)
{
    __shared__ float featl[32 * 64];

    const int t = threadIdx.x;
    const int nbase = blockIdx.x * 32;

    {
        const float4* fsrc = (const float4*)(feat + (size_t)nbase * 64);
        float4* fdst = (float4*)featl;
        fdst[t] = fsrc[t];
        fdst[t + 256] = fsrc[t + 256];
    }

    const int lane = t & 63;
    const int n0 = (t >> 6) * 8;
    const float bias = h_bias[lane];

    __syncthreads();

    constexpr int NM = (PATH == 2) ? 1 : 5;
    float acc[8][NM];
    #pragma unroll
    for (int n = 0; n < 8; ++n)
        #pragma unroll
        for (int m = 0; m < NM; ++m)
            acc[n][m] = 0.0f;

    #pragma unroll 4
    for (int i0 = 0; i0 < 64; i0 += 4) {
        float4 f4[8];
        #pragma unroll
        for (int n = 0; n < 8; ++n)
            f4[n] = *(const float4*)&featl[(n0 + n) * 64 + i0];
        #pragma unroll
        for (int q = 0; q < 4; ++q) {
            const int i = i0 + q;
            float vv[NM];
            if (PATH < 2) {
                #pragma unroll
                for (int b = 0; b < 4; ++b)
                    vv[b] = weight[b * 4096 + i * 64 + lane];
                vv[4] = loop_w[i * 64 + lane];
            } else {
                vv[0] = loop_w[i * 64 + lane];
            }
            #pragma unroll
            for (int n = 0; n < 8; ++n) {
                const float fv = (q == 0) ? f4[n].x : (q == 1) ? f4[n].y
                               : (q == 2) ? f4[n].z : f4[n].w;
                #pragma unroll
                for (int m = 0; m < NM; ++m)
                    acc[n][m] = fmaf(fv, vv[m], acc[n][m]);
            }
        }
    }

    float wc[8][4];
    if (PATH == 0) {
        #pragma unroll
        for (int r = 0; r < 8; ++r)
            #pragma unroll
            for (int b = 0; b < 4; ++b)
                wc[r][b] = w_comp[r * 4 + b];
    }

    #pragma unroll
    for (int n = 0; n < 8; ++n) {
        const size_t gn = (size_t)(nbase + n0 + n);
        out[gn * 64 + lane] = bias + acc[n][NM - 1];
        if (PATH == 0) {
            #pragma unroll
            for (int r = 0; r < 8; ++r) {
                const float w = fmaf(wc[r][0], acc[n][0],
                                fmaf(wc[r][1], acc[n][1],
                                fmaf(wc[r][2], acc[n][2],
                                     wc[r][3] * acc[n][3])));
                table[gn * 512 + (size_t)r * 64 + lane] = __float2bfloat16(w);
            }
        } else if (PATH == 1) {
            #pragma unroll
            for (int b = 0; b < 4; ++b)
                table[gn * 256 + (size_t)b * 64 + lane] = __float2bfloat16(acc[n][b]);
        }
    }
}

__global__ __launch_bounds__(256)
void k_link(const int* __restrict__ dst, int* __restrict__ head,
            int* __restrict__ next)
{
    const int i = blockIdx.x * blockDim.x + threadIdx.x;
    const int stride = gridDim.x * blockDim.x;
    for (int e = i; e < NEDGES; e += stride) {
        const int d = dst[e];
        const int old = atomicExch(&head[d], e);
        next[e] = old;
    }
}

__global__ __launch_bounds__(256)
void k_agg(const int* __restrict__ head, const int* __restrict__ next,
           const int* __restrict__ src, const int* __restrict__ et,
           const float* __restrict__ norm,
           const __hip_bfloat16* __restrict__ wfeat,
           float* __restrict__ out)
{
    const int lane = threadIdx.x & 63;
    const int wid = (int)((blockIdx.x * blockDim.x + threadIdx.x) >> 6);
    const int n0 = wid * 8;

    int   e[8];
    float acc[8];
    #pragma unroll
    for (int k = 0; k < 8; ++k) {
        e[k] = head[n0 + k];
        acc[k] = 0.0f;
    }

    while (true) {
        bool progress = false;
        #pragma unroll
        for (int k = 0; k < 8; ++k) {
            const int ek = e[k];
            if (ek >= 0) {
                progress = true;
                const int   s = src[ek];
                const int   r = et[ek];
                const float m = norm[ek];
                const float w = __bfloat162float(
                    wfeat[(size_t)s * 512 + (size_t)r * 64 + lane]);
                acc[k] = fmaf(m, w, acc[k]);
                e[k] = next[ek];
            }
        }
        if (!progress) break;
    }

    #pragma unroll
    for (int k = 0; k < 8; ++k)
        out[(size_t)(n0 + k) * 64 + lane] += acc[k];
}

__global__ __launch_bounds__(256)
void rgcn_edge_a(const int* __restrict__ src, const int* __restrict__ dst,
                 const int* __restrict__ et, const float* __restrict__ norm,
                 const __hip_bfloat16* __restrict__ wfeat,
                 float* __restrict__ out)
{
    const int lane = threadIdx.x & 63;
    const int wid  = (int)((blockIdx.x * blockDim.x + threadIdx.x) >> 6);
    const int nw   = (int)((gridDim.x * blockDim.x) >> 6);
    for (int e = wid; e < NEDGES; e += nw) {
        const int   s  = src[e];
        const int   d  = dst[e];
        const int   r  = et[e];
        const float nm = norm[e];
        const float w  = __bfloat162float(wfeat[(size_t)s * 512 + (size_t)r * 64 + lane]);
        atomicAdd(out + (size_t)d * 64 + lane, w * nm);
    }
}

__global__ __launch_bounds__(256)
void rgcn_edge_b(const int* __restrict__ src, const int* __restrict__ dst,
                 const int* __restrict__ et, const float* __restrict__ norm,
                 const __hip_bfloat16* __restrict__ proj,
                 const float* __restrict__ w_comp,
                 float* __restrict__ out)
{
    const int lane = threadIdx.x & 63;
    const int wid  = (int)((blockIdx.x * blockDim.x + threadIdx.x) >> 6);
    const int nw   = (int)((gridDim.x * blockDim.x) >> 6);
    for (int e = wid; e < NEDGES; e += nw) {
        const int   s  = src[e];
        const int   d  = dst[e];
        const int   r  = et[e];
        const float nm = norm[e];
        const __hip_bfloat16* p = proj + (size_t)s * 256;
        float m = w_comp[r * 4 + 0] * __bfloat162float(p[lane]);
        m = fmaf(w_comp[r * 4 + 1], __bfloat162float(p[ 64 + lane]), m);
        m = fmaf(w_comp[r * 4 + 2], __bfloat162float(p[128 + lane]), m);
        m = fmaf(w_comp[r * 4 + 3], __bfloat162float(p[192 + lane]), m);
        atomicAdd(out + (size_t)d * 64 + lane, m * nm);
    }
}

__global__ __launch_bounds__(256)
void rgcn_edge_c(const int* __restrict__ src, const int* __restrict__ dst,
                 const int* __restrict__ et, const float* __restrict__ norm,
                 const float* __restrict__ feat,
                 const float* __restrict__ weight,
                 const float* __restrict__ w_comp,
                 float* __restrict__ out)
{
    __shared__ __hip_bfloat16 Vl[4 * 64 * 64];
    const int t = threadIdx.x;
    #pragma unroll
    for (int k = 0; k < 64; ++k)
        Vl[t + k * 256] = __float2bfloat16(weight[t + k * 256]);
    __syncthreads();

    const int lane = t & 63;
    const int wid  = (int)((blockIdx.x * blockDim.x + t) >> 6);
    const int nw   = (int)((gridDim.x * blockDim.x) >> 6);
    for (int e = wid; e < NEDGES; e += nw) {
        const int   s  = src[e];
        const int   d  = dst[e];
        const int   r  = et[e];
        const float nm = norm[e];
        const float wc0 = w_comp[r * 4 + 0], wc1 = w_comp[r * 4 + 1];
        const float wc2 = w_comp[r * 4 + 2], wc3 = w_comp[r * 4 + 3];
        const float f = feat[(size_t)s * 64 + lane];
        float acc = 0.0f;
        #pragma unroll 8
        for (int i = 0; i < 64; ++i) {
            const float fi = __shfl(f, i);
            float w =        wc0 * __bfloat162float(Vl[          i * 64 + lane]);
            w = fmaf(wc1, __bfloat162float(Vl[ 4096 + i * 64 + lane]), w);
            w = fmaf(wc2, __bfloat162float(Vl[ 8192 + i * 64 + lane]), w);
            w = fmaf(wc3, __bfloat162float(Vl[12288 + i * 64 + lane]), w);
            acc = fmaf(fi, w, acc);
        }
        atomicAdd(out + (size_t)d * 64 + lane, acc * nm);
    }
}

// ---------------------------------------------------------------------------
extern "C" void kernel_launch(void* const* d_in, const int* in_sizes, int n_in,
                              void* d_out, int out_size, void* d_ws, size_t ws_size,
                              hipStream_t stream) {
    const float* feat   = (const float*)d_in[0];
    const int*   src    = (const int*)  d_in[1];
    const int*   dst    = (const int*)  d_in[2];
    const int*   et     = (const int*)  d_in[3];
    const float* norm   = (const float*)d_in[4];
    const float* weight = (const float*)d_in[5];
    const float* w_comp = (const float*)d_in[6];
    const float* h_bias = (const float*)d_in[7];
    const float* loop_w = (const float*)d_in[8];
    float* out = (float*)d_out;
    char* ws = (char*)d_ws;

    const dim3 gridP(NNODES / 32);  // 3125

    if (ws_size >= WS_NEED_M) {
        // ---- fused MFMA-proj + link path ----
        __hip_bfloat16* wfeat = (__hip_bfloat16*)ws;
        int*  head = (int*)(ws + HEADE_OFF);
        int4* rec  = (int4*)(ws + REC_OFF);
        __hip_bfloat16* wcat = (__hip_bfloat16*)(ws + WCAT_OFF);

        hipMemsetAsync(head, 0xFF, (size_t)NNODES * 4, stream);
        hipLaunchKernelGGL(k_wcat, dim3(144), dim3(256), 0, stream,
                           weight, w_comp, loop_w, wcat);
        hipLaunchKernelGGL(k_fused, dim3(4687), dim3(256), 0, stream,
                           feat, wcat, h_bias, wfeat, out,
                           src, dst, et, norm, head, rec);
        hipLaunchKernelGGL(k_agg_emb, dim3(NNODES / 32), dim3(256), 0, stream,
                           head, rec, wfeat, out);
    } else if (ws_size >= WS_NEED_E) {
        // ---- round-7 proven path ----
        __hip_bfloat16* wfeat = (__hip_bfloat16*)ws;
        int*  head = (int*)(ws + HEADE_OFF);
        int4* rec  = (int4*)(ws + REC_OFF);

        hipMemsetAsync(head, 0xFF, (size_t)NNODES * 4, stream);
        hipLaunchKernelGGL(k_link_emb, dim3(2048), dim3(256), 0, stream,
                           src, dst, et, norm, head, rec);
        hipLaunchKernelGGL((rgcn_proj<0>), gridP, dim3(256), 0, stream,
                           feat, weight, w_comp, h_bias, loop_w, wfeat, out);
        hipLaunchKernelGGL(k_agg_emb, dim3(NNODES / 32), dim3(256), 0, stream,
                           head, rec, wfeat, out);
    } else if (ws_size >= WS_NEED) {
        __hip_bfloat16* wfeat = (__hip_bfloat16*)ws;
        int* head = (int*)(ws + HEAD_OFF);
        int* next = (int*)(ws + NEXT_OFF);

        hipMemsetAsync(head, 0xFF, (size_t)NNODES * 4, stream);
        hipLaunchKernelGGL(k_link, dim3(2048), dim3(256), 0, stream,
                           dst, head, next);
        hipLaunchKernelGGL((rgcn_proj<0>), gridP, dim3(256), 0, stream,
                           feat, weight, w_comp, h_bias, loop_w, wfeat, out);
        hipLaunchKernelGGL(k_agg, dim3(NNODES / 32), dim3(256), 0, stream,
                           head, next, src, et, norm, wfeat, out);
    } else if (ws_size >= WF_BYTES) {
        __hip_bfloat16* wfeat = (__hip_bfloat16*)ws;
        hipLaunchKernelGGL((rgcn_proj<0>), gridP, dim3(256), 0, stream,
                           feat, weight, w_comp, h_bias, loop_w, wfeat, out);
        hipLaunchKernelGGL(rgcn_edge_a, dim3(2048), dim3(256), 0, stream,
                           src, dst, et, norm, wfeat, out);
    } else if (ws_size >= (size_t)NNODES * 256 * 2) {
        __hip_bfloat16* proj = (__hip_bfloat16*)ws;
        hipLaunchKernelGGL((rgcn_proj<1>), gridP, dim3(256), 0, stream,
                           feat, weight, w_comp, h_bias, loop_w, proj, out);
        hipLaunchKernelGGL(rgcn_edge_b, dim3(2048), dim3(256), 0, stream,
                           src, dst, et, norm, proj, w_comp, out);
    } else {
        hipLaunchKernelGGL((rgcn_proj<2>), gridP, dim3(256), 0, stream,
                           feat, weight, w_comp, h_bias, loop_w,
                           (__hip_bfloat16*)nullptr, out);
        hipLaunchKernelGGL(rgcn_edge_c, dim3(2048), dim3(256), 0, stream,
                           src, dst, et, norm, feat, weight, w_comp, out);
    }
}